// Round 4
// baseline (775.306 us; speedup 1.0000x reference)
//
#include <hip/hip_runtime.h>
#include <math.h>

// ---------------------------------------------------------------------------
// DDI_GraphTransformer: 2x TransformerConv(H=8, C=16, D=128), N=50000, E=800000
// R3: node_attn is gather-BW bound (FETCH 398MB @3.56TB/s = full dur).
//     (a) K,V stored bf16 straight from GEMM epilogue -> gather bytes halved
//     (b) 16 lanes/node x 8ch: one 16B load per array per edge-lane
//     (c) degree-sorted node permutation -> equal-degree waves (less masking)
//     (d) layer-1 output written only as bf16 Xb (kills fp32 H1 + cvt pass)
// ---------------------------------------------------------------------------

#define HEADS 8
#define CH 16
#define DM 128
#define SCALE 0.25f

typedef __attribute__((ext_vector_type(8))) short short8;
typedef __attribute__((ext_vector_type(4))) float floatx4;

static __device__ __forceinline__ ushort f2bf(float f) {  // RNE fp32->bf16
    unsigned u = __float_as_uint(f);
    unsigned r = u + 0x7FFFu + ((u >> 16) & 1u);
    return (ushort)(r >> 16);
}
static __device__ __forceinline__ float bflo(unsigned u) {
    return __uint_as_float(u << 16);
}
static __device__ __forceinline__ float bfhi(unsigned u) {
    return __uint_as_float(u & 0xFFFF0000u);
}
static __device__ __forceinline__ unsigned pack2bf(float lo, float hi) {
    return (unsigned)f2bf(lo) | ((unsigned)f2bf(hi) << 16);
}

// ---------------- converters ------------------------------------------------
__global__ __launch_bounds__(256)
void cvt_x(const float* __restrict__ in, ushort* __restrict__ out, int n4)
{
    int i = blockIdx.x * 256 + threadIdx.x;
    if (i >= n4) return;
    float4 v = ((const float4*)in)[i];
    ushort4 s;
    s.x = f2bf(v.x); s.y = f2bf(v.y); s.z = f2bf(v.z); s.w = f2bf(v.w);
    ((ushort4*)out)[i] = s;
}

// WT[mat][n*128+k] = bf16(W[k*128+n]) for 4 weight matrices
__global__ __launch_bounds__(256)
void cvt_wT(const float* __restrict__ W0, const float* __restrict__ W1,
            const float* __restrict__ W2, const float* __restrict__ W3,
            ushort* __restrict__ WT)
{
    const float* W = (blockIdx.y == 0) ? W0 : (blockIdx.y == 1) ? W1
                   : (blockIdx.y == 2) ? W2 : W3;
    int idx = blockIdx.x * 256 + threadIdx.x;   // 0..16383
    int n = idx >> 7, k = idx & 127;
    WT[(size_t)blockIdx.y * 16384 + idx] = f2bf(W[k * 128 + n]);
}

// ---------------- bf16 MFMA GEMM: {Q,Y}=f32, {K,V}=bf16 outputs -------------
#define AP 136   // LDS row pitch in shorts

__global__ __launch_bounds__(256)
void gemm_mfma(const ushort* __restrict__ Xb, const ushort* __restrict__ WT,
               const float* __restrict__ bq, const float* __restrict__ bk,
               const float* __restrict__ bv, const float* __restrict__ bsk,
               float* __restrict__ Qo, ushort* __restrict__ Kb,
               ushort* __restrict__ Vb, float* __restrict__ Yo, int N)
{
    __shared__ ushort As[128 * AP];
    __shared__ ushort Bs[64 * AP];

    const int by   = blockIdx.y;
    const int mat  = by >> 1;
    const int half = by & 1;
    const float* bias = (mat == 0) ? bq : (mat == 1) ? bk : (mat == 2) ? bv : bsk;
    const int row0 = blockIdx.x * 128;
    const int tid  = threadIdx.x;

    #pragma unroll
    for (int i = 0; i < 8; ++i) {
        int id = tid + i * 256;
        int r = id >> 4, ch = id & 15;
        uint4 v = make_uint4(0, 0, 0, 0);
        if (row0 + r < N)
            v = *(const uint4*)(Xb + (size_t)(row0 + r) * DM + ch * 8);
        *(uint4*)(As + r * AP + ch * 8) = v;
    }
    const ushort* Wt = WT + (size_t)mat * 16384 + (size_t)(half * 64) * DM;
    #pragma unroll
    for (int i = 0; i < 4; ++i) {
        int id = tid + i * 256;
        int r = id >> 4, ch = id & 15;
        uint4 v = *(const uint4*)(Wt + (size_t)r * DM + ch * 8);
        *(uint4*)(Bs + r * AP + ch * 8) = v;
    }
    __syncthreads();

    const int lane = tid & 63, w = tid >> 6;
    const int mq = (w >> 1) * 64;
    const int nqw = (w & 1) * 32;
    const int lr = lane & 15, lq = lane >> 4;

    floatx4 acc[4][2] = {};
    #pragma unroll
    for (int ks = 0; ks < 4; ++ks) {
        const int koff = ks * 32 + lq * 8;
        short8 a[4], b[2];
        #pragma unroll
        for (int t = 0; t < 4; ++t)
            a[t] = *(const short8*)(As + (mq + t * 16 + lr) * AP + koff);
        #pragma unroll
        for (int t = 0; t < 2; ++t)
            b[t] = *(const short8*)(Bs + (nqw + t * 16 + lr) * AP + koff);
        #pragma unroll
        for (int mt = 0; mt < 4; ++mt)
            #pragma unroll
            for (int nt = 0; nt < 2; ++nt)
                acc[mt][nt] = __builtin_amdgcn_mfma_f32_16x16x32_bf16(
                    a[mt], b[nt], acc[mt][nt], 0, 0, 0);
    }

    // epilogue: C/D layout col=lane&15, row=(lane>>4)*4+reg
    if (mat == 1 || mat == 2) {                 // K,V -> bf16
        ushort* OutB = (mat == 1) ? Kb : Vb;
        #pragma unroll
        for (int nt = 0; nt < 2; ++nt) {
            const int col = half * 64 + nqw + nt * 16 + lr;
            const float bcol = bias[col];
            #pragma unroll
            for (int mt = 0; mt < 4; ++mt) {
                const int rbase = row0 + mq + mt * 16 + lq * 4;
                #pragma unroll
                for (int r = 0; r < 4; ++r) {
                    const int row = rbase + r;
                    if (row < N)
                        OutB[(size_t)row * DM + col] = f2bf(acc[mt][nt][r] + bcol);
                }
            }
        }
    } else {                                     // Q, skip -> f32
        float* Out = (mat == 0) ? Qo : Yo;
        #pragma unroll
        for (int nt = 0; nt < 2; ++nt) {
            const int col = half * 64 + nqw + nt * 16 + lr;
            const float bcol = bias[col];
            #pragma unroll
            for (int mt = 0; mt < 4; ++mt) {
                const int rbase = row0 + mq + mt * 16 + lq * 4;
                #pragma unroll
                for (int r = 0; r < 4; ++r) {
                    const int row = rbase + r;
                    if (row < N)
                        Out[(size_t)row * DM + col] = acc[mt][nt][r] + bcol;
                }
            }
        }
    }
}

// ---------------- CSR build: histogram -> scan -> scatter --------------------
__global__ __launch_bounds__(256)
void hist_k(const int* __restrict__ dst, int* __restrict__ counts, int E)
{
    int e = blockIdx.x * blockDim.x + threadIdx.x;
    if (e < E) atomicAdd(&counts[dst[e]], 1);
}

__global__ __launch_bounds__(1024)
void scan_k(const int* __restrict__ counts, int* __restrict__ rowptr, int N)
{
    __shared__ int sdata[1024];
    const int t = threadIdx.x;
    const int chunk = (N + 1023) / 1024;
    const int begin = t * chunk;
    const int end   = min(begin + chunk, N);
    int sum = 0;
    for (int i = begin; i < end; ++i) sum += counts[i];
    sdata[t] = sum;
    __syncthreads();
    for (int off = 1; off < 1024; off <<= 1) {
        int v = (t >= off) ? sdata[t - off] : 0;
        __syncthreads();
        if (t >= off) sdata[t] += v;
        __syncthreads();
    }
    int run = (t == 0) ? 0 : sdata[t - 1];
    for (int i = begin; i < end; ++i) {
        rowptr[i] = run;
        run += counts[i];
    }
    if (t == 0) rowptr[N] = sdata[1023];
}

__global__ __launch_bounds__(256)
void scatter_k(const int* __restrict__ src, const int* __restrict__ dst,
               int* __restrict__ cursor, int* __restrict__ esrc, int E)
{
    int e = blockIdx.x * blockDim.x + threadIdx.x;
    if (e >= E) return;
    int pos = atomicAdd(&cursor[dst[e]], 1);
    esrc[pos] = src[e];
}

// ---------------- degree sort (descending counting sort, 256 bins) -----------
__global__ __launch_bounds__(256)
void dhist_k(const int* __restrict__ counts, int* __restrict__ dbins, int N)
{
    int n = blockIdx.x * 256 + threadIdx.x;
    if (n < N) atomicAdd(&dbins[min(counts[n], 255)], 1);
}

__global__ __launch_bounds__(256)
void dscan_k(const int* __restrict__ dbins, int* __restrict__ dcur)
{
    __shared__ int s[256];
    const int t = threadIdx.x;
    s[t] = dbins[255 - t];          // descending degree order
    __syncthreads();
    for (int off = 1; off < 256; off <<= 1) {
        int v = (t >= off) ? s[t - off] : 0;
        __syncthreads();
        if (t >= off) s[t] += v;
        __syncthreads();
    }
    dcur[255 - t] = (t == 0) ? 0 : s[t - 1];   // exclusive start of each bin
}

__global__ __launch_bounds__(256)
void dscatter_k(const int* __restrict__ counts, int* __restrict__ dcur,
                int* __restrict__ perm, int N)
{
    int n = blockIdx.x * 256 + threadIdx.x;
    if (n >= N) return;
    int pos = atomicAdd(&dcur[min(counts[n], 255)], 1);
    perm[pos] = n;
}

// ---------------- fused per-node attention (16 lanes/node, bf16 K/V) ---------
// Yout!=null: write fp32 (+skip Yin). Bout!=null: write bf16 (layer-2 input).
__global__ __launch_bounds__(256)
void node_attn(const float* __restrict__ Q, const ushort* __restrict__ Kb,
               const ushort* __restrict__ Vb,
               const int* __restrict__ rowptr, const int* __restrict__ esrc,
               const int* __restrict__ perm,
               const float* __restrict__ Yin, float* __restrict__ Yout,
               ushort* __restrict__ Bout, int N, int relu)
{
    const int idx = blockIdx.x * 16 + (threadIdx.x >> 4);
    if (idx >= N) return;
    const int nid = perm[idx];
    const int c8 = (threadIdx.x & 15) * 8;      // 8 channels/lane; head=c8>>4
    float q[8];
    *(float4*)(q)     = *(const float4*)(Q + (size_t)nid * DM + c8);
    *(float4*)(q + 4) = *(const float4*)(Q + (size_t)nid * DM + c8 + 4);
    const int beg = rowptr[nid], end = rowptr[nid + 1];

    float m = -INFINITY, l = 0.f;
    float acc[8] = {0.f};
    for (int i = beg; i < end; ++i) {
        const int s = esrc[i];
        const uint4 kr = *(const uint4*)(Kb + (size_t)s * DM + c8);
        const uint4 vr = *(const uint4*)(Vb + (size_t)s * DM + c8);
        float va[8];
        va[0] = bflo(vr.x); va[1] = bfhi(vr.x);
        va[2] = bflo(vr.y); va[3] = bfhi(vr.y);
        va[4] = bflo(vr.z); va[5] = bfhi(vr.z);
        va[6] = bflo(vr.w); va[7] = bfhi(vr.w);
        float p;
        p = q[0] * bflo(kr.x);
        p = fmaf(q[1], bfhi(kr.x), p);
        p = fmaf(q[2], bflo(kr.y), p);
        p = fmaf(q[3], bfhi(kr.y), p);
        p = fmaf(q[4], bflo(kr.z), p);
        p = fmaf(q[5], bfhi(kr.z), p);
        p = fmaf(q[6], bflo(kr.w), p);
        p = fmaf(q[7], bfhi(kr.w), p);
        p += __shfl_xor(p, 1, 2);               // pair-lanes = one head
        p *= SCALE;
        if (p <= m) {
            const float wgt = __expf(p - m);
            l += wgt;
            #pragma unroll
            for (int j = 0; j < 8; ++j) acc[j] = fmaf(wgt, va[j], acc[j]);
        } else {
            const float r = __expf(m - p);      // 0 on first edge
            l = fmaf(l, r, 1.f);
            #pragma unroll
            for (int j = 0; j < 8; ++j) acc[j] = fmaf(acc[j], r, va[j]);
            m = p;
        }
    }
    const float inv = (l > 0.f) ? 1.f / l : 0.f;
    float y[8];
    *(float4*)(y)     = *(const float4*)(Yin + (size_t)nid * DM + c8);
    *(float4*)(y + 4) = *(const float4*)(Yin + (size_t)nid * DM + c8 + 4);
    #pragma unroll
    for (int j = 0; j < 8; ++j) {
        y[j] = fmaf(acc[j], inv, y[j]);
        if (relu) y[j] = fmaxf(y[j], 0.f);
    }
    if (Yout) {
        *(float4*)(Yout + (size_t)nid * DM + c8)     = *(float4*)(y);
        *(float4*)(Yout + (size_t)nid * DM + c8 + 4) = *(float4*)(y + 4);
    }
    if (Bout) {
        uint4 o;
        o.x = pack2bf(y[0], y[1]); o.y = pack2bf(y[2], y[3]);
        o.z = pack2bf(y[4], y[5]); o.w = pack2bf(y[6], y[7]);
        *(uint4*)(Bout + (size_t)nid * DM + c8) = o;
    }
}

// ---------------------------------------------------------------------------
extern "C" void kernel_launch(void* const* d_in, const int* in_sizes, int n_in,
                              void* d_out, int out_size, void* d_ws, size_t ws_size,
                              hipStream_t stream)
{
    const float* x   = (const float*)d_in[0];
    const int* eidx  = (const int*)d_in[1];
    const float* qw0 = (const float*)d_in[3];  const float* qb0 = (const float*)d_in[4];
    const float* kw0 = (const float*)d_in[5];  const float* kb0 = (const float*)d_in[6];
    const float* vw0 = (const float*)d_in[7];  const float* vb0 = (const float*)d_in[8];
    const float* sw0 = (const float*)d_in[9];  const float* sb0 = (const float*)d_in[10];
    const float* qw1 = (const float*)d_in[11]; const float* qb1 = (const float*)d_in[12];
    const float* kw1 = (const float*)d_in[13]; const float* kb1 = (const float*)d_in[14];
    const float* vw1 = (const float*)d_in[15]; const float* vb1 = (const float*)d_in[16];
    const float* sw1 = (const float*)d_in[17]; const float* sb1 = (const float*)d_in[18];

    const int N = in_sizes[0] / DM;
    const int E = in_sizes[1] / 2;
    const int* src = eidx;
    const int* dst = eidx + E;

    // ws: Q,S1 [N*128 f32] | Kb,Vb,Xb [N*128 bf16] | WT [4*16384 bf16]
    //     | counts[N] rowptr[N+1] cursor[N] esrc[E] perm[N] dbins[256] dcur[256]
    float* ws  = (float*)d_ws;
    size_t nd  = (size_t)N * DM;
    float* Q   = ws;
    float* S1  = Q + nd;
    ushort* Kb = (ushort*)(S1 + nd);
    ushort* Vb = Kb + nd;
    ushort* Xb = Vb + nd;
    ushort* WT = Xb + nd;
    int* counts = (int*)(WT + 4 * 16384);
    int* rowptr = counts + N;
    int* cursor = rowptr + (N + 1);
    int* esrc   = cursor + N;
    int* perm   = esrc + E;
    int* dbins  = perm + N;
    int* dcur   = dbins + 256;
    float* out  = (float*)d_out;

    // ---- CSR + degree-sorted permutation (shared by both layers) ----
    hipMemsetAsync(counts, 0, (size_t)N * sizeof(int), stream);
    hipMemsetAsync(dbins, 0, 256 * sizeof(int), stream);
    hist_k<<<(E + 255) / 256, 256, 0, stream>>>(dst, counts, E);
    scan_k<<<1, 1024, 0, stream>>>(counts, rowptr, N);
    hipMemcpyAsync(cursor, rowptr, (size_t)N * sizeof(int),
                   hipMemcpyDeviceToDevice, stream);
    scatter_k<<<(E + 255) / 256, 256, 0, stream>>>(src, dst, cursor, esrc, E);
    dhist_k<<<(N + 255) / 256, 256, 0, stream>>>(counts, dbins, N);
    dscan_k<<<1, 256, 0, stream>>>(dbins, dcur);
    dscatter_k<<<(N + 255) / 256, 256, 0, stream>>>(counts, dcur, perm, N);

    const int n4 = N * (DM / 4);
    dim3 ggrid((N + 127) / 128, 8);
    const int ablk = (N + 15) / 16;

    // ---- layer 1: x -> Xb (bf16, relu'd, skip-added) ----
    cvt_x<<<(n4 + 255) / 256, 256, 0, stream>>>(x, Xb, n4);
    cvt_wT<<<dim3(64, 4), 256, 0, stream>>>(qw0, kw0, vw0, sw0, WT);
    gemm_mfma<<<ggrid, 256, 0, stream>>>(Xb, WT, qb0, kb0, vb0, sb0,
                                         Q, Kb, Vb, S1, N);
    node_attn<<<ablk, 256, 0, stream>>>(Q, Kb, Vb, rowptr, esrc, perm,
                                        S1, nullptr, Xb, N, 1);

    // ---- layer 2: Xb -> out (fp32) ----
    cvt_wT<<<dim3(64, 4), 256, 0, stream>>>(qw1, kw1, vw1, sw1, WT);
    gemm_mfma<<<ggrid, 256, 0, stream>>>(Xb, WT, qb1, kb1, vb1, sb1,
                                         Q, Kb, Vb, out, N);
    node_attn<<<ablk, 256, 0, stream>>>(Q, Kb, Vb, rowptr, esrc, perm,
                                        out, out, nullptr, N, 0);
}

// Round 5
// 657.535 us; speedup vs baseline: 1.1791x; 1.1791x over previous
//
#include <hip/hip_runtime.h>
#include <math.h>

// ---------------------------------------------------------------------------
// DDI_GraphTransformer: 2x TransformerConv(H=8, C=16, D=128), N=50000, E=800000
// R4 post-mortem: dscatter_k 140us (50k atomics on ~30 bins); node_attn lost
//   its MLP when lanes/node halved.
// R5: (a) LDS-binned dscatter (per-block hist + 1 global atomic per bin)
//     (b) node_attn: 32 lanes/node (R3 concurrency) x uint2 bf16 loads
//         (R4 bytes) -> same loads-in-flight, half traffic.
// ---------------------------------------------------------------------------

#define HEADS 8
#define CH 16
#define DM 128
#define SCALE 0.25f

typedef __attribute__((ext_vector_type(8))) short short8;
typedef __attribute__((ext_vector_type(4))) float floatx4;

static __device__ __forceinline__ ushort f2bf(float f) {  // RNE fp32->bf16
    unsigned u = __float_as_uint(f);
    unsigned r = u + 0x7FFFu + ((u >> 16) & 1u);
    return (ushort)(r >> 16);
}
static __device__ __forceinline__ float bflo(unsigned u) {
    return __uint_as_float(u << 16);
}
static __device__ __forceinline__ float bfhi(unsigned u) {
    return __uint_as_float(u & 0xFFFF0000u);
}
static __device__ __forceinline__ unsigned pack2bf(float lo, float hi) {
    return (unsigned)f2bf(lo) | ((unsigned)f2bf(hi) << 16);
}

// ---------------- converters ------------------------------------------------
__global__ __launch_bounds__(256)
void cvt_x(const float* __restrict__ in, ushort* __restrict__ out, int n4)
{
    int i = blockIdx.x * 256 + threadIdx.x;
    if (i >= n4) return;
    float4 v = ((const float4*)in)[i];
    ushort4 s;
    s.x = f2bf(v.x); s.y = f2bf(v.y); s.z = f2bf(v.z); s.w = f2bf(v.w);
    ((ushort4*)out)[i] = s;
}

// WT[mat][n*128+k] = bf16(W[k*128+n]) for 4 weight matrices
__global__ __launch_bounds__(256)
void cvt_wT(const float* __restrict__ W0, const float* __restrict__ W1,
            const float* __restrict__ W2, const float* __restrict__ W3,
            ushort* __restrict__ WT)
{
    const float* W = (blockIdx.y == 0) ? W0 : (blockIdx.y == 1) ? W1
                   : (blockIdx.y == 2) ? W2 : W3;
    int idx = blockIdx.x * 256 + threadIdx.x;   // 0..16383
    int n = idx >> 7, k = idx & 127;
    WT[(size_t)blockIdx.y * 16384 + idx] = f2bf(W[k * 128 + n]);
}

// ---------------- bf16 MFMA GEMM: {Q,Y}=f32, {K,V}=bf16 outputs -------------
#define AP 136   // LDS row pitch in shorts

__global__ __launch_bounds__(256)
void gemm_mfma(const ushort* __restrict__ Xb, const ushort* __restrict__ WT,
               const float* __restrict__ bq, const float* __restrict__ bk,
               const float* __restrict__ bv, const float* __restrict__ bsk,
               float* __restrict__ Qo, ushort* __restrict__ Kb,
               ushort* __restrict__ Vb, float* __restrict__ Yo, int N)
{
    __shared__ ushort As[128 * AP];
    __shared__ ushort Bs[64 * AP];

    const int by   = blockIdx.y;
    const int mat  = by >> 1;
    const int half = by & 1;
    const float* bias = (mat == 0) ? bq : (mat == 1) ? bk : (mat == 2) ? bv : bsk;
    const int row0 = blockIdx.x * 128;
    const int tid  = threadIdx.x;

    #pragma unroll
    for (int i = 0; i < 8; ++i) {
        int id = tid + i * 256;
        int r = id >> 4, ch = id & 15;
        uint4 v = make_uint4(0, 0, 0, 0);
        if (row0 + r < N)
            v = *(const uint4*)(Xb + (size_t)(row0 + r) * DM + ch * 8);
        *(uint4*)(As + r * AP + ch * 8) = v;
    }
    const ushort* Wt = WT + (size_t)mat * 16384 + (size_t)(half * 64) * DM;
    #pragma unroll
    for (int i = 0; i < 4; ++i) {
        int id = tid + i * 256;
        int r = id >> 4, ch = id & 15;
        uint4 v = *(const uint4*)(Wt + (size_t)r * DM + ch * 8);
        *(uint4*)(Bs + r * AP + ch * 8) = v;
    }
    __syncthreads();

    const int lane = tid & 63, w = tid >> 6;
    const int mq = (w >> 1) * 64;
    const int nqw = (w & 1) * 32;
    const int lr = lane & 15, lq = lane >> 4;

    floatx4 acc[4][2] = {};
    #pragma unroll
    for (int ks = 0; ks < 4; ++ks) {
        const int koff = ks * 32 + lq * 8;
        short8 a[4], b[2];
        #pragma unroll
        for (int t = 0; t < 4; ++t)
            a[t] = *(const short8*)(As + (mq + t * 16 + lr) * AP + koff);
        #pragma unroll
        for (int t = 0; t < 2; ++t)
            b[t] = *(const short8*)(Bs + (nqw + t * 16 + lr) * AP + koff);
        #pragma unroll
        for (int mt = 0; mt < 4; ++mt)
            #pragma unroll
            for (int nt = 0; nt < 2; ++nt)
                acc[mt][nt] = __builtin_amdgcn_mfma_f32_16x16x32_bf16(
                    a[mt], b[nt], acc[mt][nt], 0, 0, 0);
    }

    // epilogue: C/D layout col=lane&15, row=(lane>>4)*4+reg
    if (mat == 1 || mat == 2) {                 // K,V -> bf16
        ushort* OutB = (mat == 1) ? Kb : Vb;
        #pragma unroll
        for (int nt = 0; nt < 2; ++nt) {
            const int col = half * 64 + nqw + nt * 16 + lr;
            const float bcol = bias[col];
            #pragma unroll
            for (int mt = 0; mt < 4; ++mt) {
                const int rbase = row0 + mq + mt * 16 + lq * 4;
                #pragma unroll
                for (int r = 0; r < 4; ++r) {
                    const int row = rbase + r;
                    if (row < N)
                        OutB[(size_t)row * DM + col] = f2bf(acc[mt][nt][r] + bcol);
                }
            }
        }
    } else {                                     // Q, skip -> f32
        float* Out = (mat == 0) ? Qo : Yo;
        #pragma unroll
        for (int nt = 0; nt < 2; ++nt) {
            const int col = half * 64 + nqw + nt * 16 + lr;
            const float bcol = bias[col];
            #pragma unroll
            for (int mt = 0; mt < 4; ++mt) {
                const int rbase = row0 + mq + mt * 16 + lq * 4;
                #pragma unroll
                for (int r = 0; r < 4; ++r) {
                    const int row = rbase + r;
                    if (row < N)
                        Out[(size_t)row * DM + col] = acc[mt][nt][r] + bcol;
                }
            }
        }
    }
}

// ---------------- CSR build: histogram -> scan -> scatter --------------------
__global__ __launch_bounds__(256)
void hist_k(const int* __restrict__ dst, int* __restrict__ counts, int E)
{
    int e = blockIdx.x * blockDim.x + threadIdx.x;
    if (e < E) atomicAdd(&counts[dst[e]], 1);
}

__global__ __launch_bounds__(1024)
void scan_k(const int* __restrict__ counts, int* __restrict__ rowptr, int N)
{
    __shared__ int sdata[1024];
    const int t = threadIdx.x;
    const int chunk = (N + 1023) / 1024;
    const int begin = t * chunk;
    const int end   = min(begin + chunk, N);
    int sum = 0;
    for (int i = begin; i < end; ++i) sum += counts[i];
    sdata[t] = sum;
    __syncthreads();
    for (int off = 1; off < 1024; off <<= 1) {
        int v = (t >= off) ? sdata[t - off] : 0;
        __syncthreads();
        if (t >= off) sdata[t] += v;
        __syncthreads();
    }
    int run = (t == 0) ? 0 : sdata[t - 1];
    for (int i = begin; i < end; ++i) {
        rowptr[i] = run;
        run += counts[i];
    }
    if (t == 0) rowptr[N] = sdata[1023];
}

__global__ __launch_bounds__(256)
void scatter_k(const int* __restrict__ src, const int* __restrict__ dst,
               int* __restrict__ cursor, int* __restrict__ esrc, int E)
{
    int e = blockIdx.x * blockDim.x + threadIdx.x;
    if (e >= E) return;
    int pos = atomicAdd(&cursor[dst[e]], 1);
    esrc[pos] = src[e];
}

// ---------------- degree sort (descending counting sort, 256 bins) -----------
__global__ __launch_bounds__(256)
void dhist_k(const int* __restrict__ counts, int* __restrict__ dbins, int N)
{
    int n = blockIdx.x * 256 + threadIdx.x;
    if (n < N) atomicAdd(&dbins[min(counts[n], 255)], 1);
}

__global__ __launch_bounds__(256)
void dscan_k(const int* __restrict__ dbins, int* __restrict__ dcur)
{
    __shared__ int s[256];
    const int t = threadIdx.x;
    s[t] = dbins[255 - t];          // descending degree order
    __syncthreads();
    for (int off = 1; off < 256; off <<= 1) {
        int v = (t >= off) ? s[t - off] : 0;
        __syncthreads();
        if (t >= off) s[t] += v;
        __syncthreads();
    }
    dcur[255 - t] = (t == 0) ? 0 : s[t - 1];   // exclusive start of each bin
}

// LDS-binned: per-block LDS histogram, ONE global atomic per (block, bin)
__global__ __launch_bounds__(256)
void dscatter_k(const int* __restrict__ counts, int* __restrict__ dcur,
                int* __restrict__ perm, int N)
{
    __shared__ int lc[256];     // per-bin count within this block
    __shared__ int lbase[256];  // global base reserved for this block's bin
    const int t = threadIdx.x;
    lc[t] = 0;
    __syncthreads();
    const int n = blockIdx.x * 256 + t;
    int bin = 0, rank = 0;
    const bool valid = (n < N);
    if (valid) {
        bin = min(counts[n], 255);
        rank = atomicAdd(&lc[bin], 1);          // LDS atomic: cheap
    }
    __syncthreads();
    if (lc[t] > 0) lbase[t] = atomicAdd(&dcur[t], lc[t]);
    __syncthreads();
    if (valid) perm[lbase[bin] + rank] = n;
}

// ---------------- fused per-node attention (32 lanes/node, bf16 K/V) ---------
// Yout!=null: write fp32 (+skip Yin). Bout!=null: write bf16 (layer-2 input).
__global__ __launch_bounds__(256)
void node_attn(const float* __restrict__ Q, const ushort* __restrict__ Kb,
               const ushort* __restrict__ Vb,
               const int* __restrict__ rowptr, const int* __restrict__ esrc,
               const int* __restrict__ perm,
               const float* __restrict__ Yin, float* __restrict__ Yout,
               ushort* __restrict__ Bout, int N, int relu)
{
    const int idx = blockIdx.x * 8 + (threadIdx.x >> 5);
    if (idx >= N) return;
    const int nid = perm[idx];
    const int c4 = (threadIdx.x & 31) * 4;      // 4 channels/lane; head=c4>>4
    const float4 q = *(const float4*)(Q + (size_t)nid * DM + c4);
    const int beg = rowptr[nid], end = rowptr[nid + 1];

    float m = -INFINITY, l = 0.f;
    float a0 = 0.f, a1 = 0.f, a2 = 0.f, a3 = 0.f;
    for (int i = beg; i < end; ++i) {
        const int s = esrc[i];
        const uint2 kr = *(const uint2*)(Kb + (size_t)s * DM + c4);
        const uint2 vr = *(const uint2*)(Vb + (size_t)s * DM + c4);
        float p = q.x * bflo(kr.x);
        p = fmaf(q.y, bfhi(kr.x), p);
        p = fmaf(q.z, bflo(kr.y), p);
        p = fmaf(q.w, bfhi(kr.y), p);
        p += __shfl_xor(p, 1, 4);               // head = 4 lanes
        p += __shfl_xor(p, 2, 4);
        p *= SCALE;
        const float v0 = bflo(vr.x), v1 = bfhi(vr.x);
        const float v2 = bflo(vr.y), v3 = bfhi(vr.y);
        if (p <= m) {                            // common case: 1 exp
            const float wgt = __expf(p - m);
            l += wgt;
            a0 = fmaf(wgt, v0, a0); a1 = fmaf(wgt, v1, a1);
            a2 = fmaf(wgt, v2, a2); a3 = fmaf(wgt, v3, a3);
        } else {                                 // new max: rescale
            const float r = __expf(m - p);       // 0 on first edge
            l = fmaf(l, r, 1.f);
            a0 = fmaf(a0, r, v0); a1 = fmaf(a1, r, v1);
            a2 = fmaf(a2, r, v2); a3 = fmaf(a3, r, v3);
            m = p;
        }
    }
    const float inv = (l > 0.f) ? 1.f / l : 0.f;
    float4 y = *(const float4*)(Yin + (size_t)nid * DM + c4);
    y.x = fmaf(a0, inv, y.x); y.y = fmaf(a1, inv, y.y);
    y.z = fmaf(a2, inv, y.z); y.w = fmaf(a3, inv, y.w);
    if (relu) {
        y.x = fmaxf(y.x, 0.f); y.y = fmaxf(y.y, 0.f);
        y.z = fmaxf(y.z, 0.f); y.w = fmaxf(y.w, 0.f);
    }
    if (Yout) *(float4*)(Yout + (size_t)nid * DM + c4) = y;
    if (Bout) {
        uint2 o;
        o.x = pack2bf(y.x, y.y);
        o.y = pack2bf(y.z, y.w);
        *(uint2*)(Bout + (size_t)nid * DM + c4) = o;
    }
}

// ---------------------------------------------------------------------------
extern "C" void kernel_launch(void* const* d_in, const int* in_sizes, int n_in,
                              void* d_out, int out_size, void* d_ws, size_t ws_size,
                              hipStream_t stream)
{
    const float* x   = (const float*)d_in[0];
    const int* eidx  = (const int*)d_in[1];
    const float* qw0 = (const float*)d_in[3];  const float* qb0 = (const float*)d_in[4];
    const float* kw0 = (const float*)d_in[5];  const float* kb0 = (const float*)d_in[6];
    const float* vw0 = (const float*)d_in[7];  const float* vb0 = (const float*)d_in[8];
    const float* sw0 = (const float*)d_in[9];  const float* sb0 = (const float*)d_in[10];
    const float* qw1 = (const float*)d_in[11]; const float* qb1 = (const float*)d_in[12];
    const float* kw1 = (const float*)d_in[13]; const float* kb1 = (const float*)d_in[14];
    const float* vw1 = (const float*)d_in[15]; const float* vb1 = (const float*)d_in[16];
    const float* sw1 = (const float*)d_in[17]; const float* sb1 = (const float*)d_in[18];

    const int N = in_sizes[0] / DM;
    const int E = in_sizes[1] / 2;
    const int* src = eidx;
    const int* dst = eidx + E;

    // ws: Q,S1 [N*128 f32] | Kb,Vb,Xb [N*128 bf16] | WT [4*16384 bf16]
    //     | counts[N] rowptr[N+1] cursor[N] esrc[E] perm[N] dbins[256] dcur[256]
    float* ws  = (float*)d_ws;
    size_t nd  = (size_t)N * DM;
    float* Q   = ws;
    float* S1  = Q + nd;
    ushort* Kb = (ushort*)(S1 + nd);
    ushort* Vb = Kb + nd;
    ushort* Xb = Vb + nd;
    ushort* WT = Xb + nd;
    int* counts = (int*)(WT + 4 * 16384);
    int* rowptr = counts + N;
    int* cursor = rowptr + (N + 1);
    int* esrc   = cursor + N;
    int* perm   = esrc + E;
    int* dbins  = perm + N;
    int* dcur   = dbins + 256;
    float* out  = (float*)d_out;

    // ---- CSR + degree-sorted permutation (shared by both layers) ----
    hipMemsetAsync(counts, 0, (size_t)N * sizeof(int), stream);
    hipMemsetAsync(dbins, 0, 256 * sizeof(int), stream);
    hist_k<<<(E + 255) / 256, 256, 0, stream>>>(dst, counts, E);
    scan_k<<<1, 1024, 0, stream>>>(counts, rowptr, N);
    hipMemcpyAsync(cursor, rowptr, (size_t)N * sizeof(int),
                   hipMemcpyDeviceToDevice, stream);
    scatter_k<<<(E + 255) / 256, 256, 0, stream>>>(src, dst, cursor, esrc, E);
    dhist_k<<<(N + 255) / 256, 256, 0, stream>>>(counts, dbins, N);
    dscan_k<<<1, 256, 0, stream>>>(dbins, dcur);
    dscatter_k<<<(N + 255) / 256, 256, 0, stream>>>(counts, dcur, perm, N);

    const int n4 = N * (DM / 4);
    dim3 ggrid((N + 127) / 128, 8);
    const int ablk = (N + 7) / 8;

    // ---- layer 1: x -> Xb (bf16, relu'd, skip-added) ----
    cvt_x<<<(n4 + 255) / 256, 256, 0, stream>>>(x, Xb, n4);
    cvt_wT<<<dim3(64, 4), 256, 0, stream>>>(qw0, kw0, vw0, sw0, WT);
    gemm_mfma<<<ggrid, 256, 0, stream>>>(Xb, WT, qb0, kb0, vb0, sb0,
                                         Q, Kb, Vb, S1, N);
    node_attn<<<ablk, 256, 0, stream>>>(Q, Kb, Vb, rowptr, esrc, perm,
                                        S1, nullptr, Xb, N, 1);

    // ---- layer 2: Xb -> out (fp32) ----
    cvt_wT<<<dim3(64, 4), 256, 0, stream>>>(qw1, kw1, vw1, sw1, WT);
    gemm_mfma<<<ggrid, 256, 0, stream>>>(Xb, WT, qb1, kb1, vb1, sb1,
                                         Q, Kb, Vb, out, N);
    node_attn<<<ablk, 256, 0, stream>>>(Q, Kb, Vb, rowptr, esrc, perm,
                                        out, out, nullptr, N, 0);
}

// Round 6
// 530.584 us; speedup vs baseline: 1.4612x; 1.2393x over previous
//
#include <hip/hip_runtime.h>
#include <math.h>

// ---------------------------------------------------------------------------
// DDI_GraphTransformer: 2x TransformerConv(H=8, C=16, D=128), N=50000, E=800000
// R5 post-mortem: dscatter LDS-binning worked (off top-5); dhist_k has the
//   SAME bug (50k global atomics on ~30 hot degree bins -> 138us serialized).
// R6: dhist_k -> per-block LDS histogram + one global atomic per bin.
// ---------------------------------------------------------------------------

#define HEADS 8
#define CH 16
#define DM 128
#define SCALE 0.25f

typedef __attribute__((ext_vector_type(8))) short short8;
typedef __attribute__((ext_vector_type(4))) float floatx4;

static __device__ __forceinline__ ushort f2bf(float f) {  // RNE fp32->bf16
    unsigned u = __float_as_uint(f);
    unsigned r = u + 0x7FFFu + ((u >> 16) & 1u);
    return (ushort)(r >> 16);
}
static __device__ __forceinline__ float bflo(unsigned u) {
    return __uint_as_float(u << 16);
}
static __device__ __forceinline__ float bfhi(unsigned u) {
    return __uint_as_float(u & 0xFFFF0000u);
}
static __device__ __forceinline__ unsigned pack2bf(float lo, float hi) {
    return (unsigned)f2bf(lo) | ((unsigned)f2bf(hi) << 16);
}

// ---------------- converters ------------------------------------------------
__global__ __launch_bounds__(256)
void cvt_x(const float* __restrict__ in, ushort* __restrict__ out, int n4)
{
    int i = blockIdx.x * 256 + threadIdx.x;
    if (i >= n4) return;
    float4 v = ((const float4*)in)[i];
    ushort4 s;
    s.x = f2bf(v.x); s.y = f2bf(v.y); s.z = f2bf(v.z); s.w = f2bf(v.w);
    ((ushort4*)out)[i] = s;
}

// WT[mat][n*128+k] = bf16(W[k*128+n]) for 4 weight matrices
__global__ __launch_bounds__(256)
void cvt_wT(const float* __restrict__ W0, const float* __restrict__ W1,
            const float* __restrict__ W2, const float* __restrict__ W3,
            ushort* __restrict__ WT)
{
    const float* W = (blockIdx.y == 0) ? W0 : (blockIdx.y == 1) ? W1
                   : (blockIdx.y == 2) ? W2 : W3;
    int idx = blockIdx.x * 256 + threadIdx.x;   // 0..16383
    int n = idx >> 7, k = idx & 127;
    WT[(size_t)blockIdx.y * 16384 + idx] = f2bf(W[k * 128 + n]);
}

// ---------------- bf16 MFMA GEMM: {Q,Y}=f32, {K,V}=bf16 outputs -------------
#define AP 136   // LDS row pitch in shorts

__global__ __launch_bounds__(256)
void gemm_mfma(const ushort* __restrict__ Xb, const ushort* __restrict__ WT,
               const float* __restrict__ bq, const float* __restrict__ bk,
               const float* __restrict__ bv, const float* __restrict__ bsk,
               float* __restrict__ Qo, ushort* __restrict__ Kb,
               ushort* __restrict__ Vb, float* __restrict__ Yo, int N)
{
    __shared__ ushort As[128 * AP];
    __shared__ ushort Bs[64 * AP];

    const int by   = blockIdx.y;
    const int mat  = by >> 1;
    const int half = by & 1;
    const float* bias = (mat == 0) ? bq : (mat == 1) ? bk : (mat == 2) ? bv : bsk;
    const int row0 = blockIdx.x * 128;
    const int tid  = threadIdx.x;

    #pragma unroll
    for (int i = 0; i < 8; ++i) {
        int id = tid + i * 256;
        int r = id >> 4, ch = id & 15;
        uint4 v = make_uint4(0, 0, 0, 0);
        if (row0 + r < N)
            v = *(const uint4*)(Xb + (size_t)(row0 + r) * DM + ch * 8);
        *(uint4*)(As + r * AP + ch * 8) = v;
    }
    const ushort* Wt = WT + (size_t)mat * 16384 + (size_t)(half * 64) * DM;
    #pragma unroll
    for (int i = 0; i < 4; ++i) {
        int id = tid + i * 256;
        int r = id >> 4, ch = id & 15;
        uint4 v = *(const uint4*)(Wt + (size_t)r * DM + ch * 8);
        *(uint4*)(Bs + r * AP + ch * 8) = v;
    }
    __syncthreads();

    const int lane = tid & 63, w = tid >> 6;
    const int mq = (w >> 1) * 64;
    const int nqw = (w & 1) * 32;
    const int lr = lane & 15, lq = lane >> 4;

    floatx4 acc[4][2] = {};
    #pragma unroll
    for (int ks = 0; ks < 4; ++ks) {
        const int koff = ks * 32 + lq * 8;
        short8 a[4], b[2];
        #pragma unroll
        for (int t = 0; t < 4; ++t)
            a[t] = *(const short8*)(As + (mq + t * 16 + lr) * AP + koff);
        #pragma unroll
        for (int t = 0; t < 2; ++t)
            b[t] = *(const short8*)(Bs + (nqw + t * 16 + lr) * AP + koff);
        #pragma unroll
        for (int mt = 0; mt < 4; ++mt)
            #pragma unroll
            for (int nt = 0; nt < 2; ++nt)
                acc[mt][nt] = __builtin_amdgcn_mfma_f32_16x16x32_bf16(
                    a[mt], b[nt], acc[mt][nt], 0, 0, 0);
    }

    // epilogue: C/D layout col=lane&15, row=(lane>>4)*4+reg
    if (mat == 1 || mat == 2) {                 // K,V -> bf16
        ushort* OutB = (mat == 1) ? Kb : Vb;
        #pragma unroll
        for (int nt = 0; nt < 2; ++nt) {
            const int col = half * 64 + nqw + nt * 16 + lr;
            const float bcol = bias[col];
            #pragma unroll
            for (int mt = 0; mt < 4; ++mt) {
                const int rbase = row0 + mq + mt * 16 + lq * 4;
                #pragma unroll
                for (int r = 0; r < 4; ++r) {
                    const int row = rbase + r;
                    if (row < N)
                        OutB[(size_t)row * DM + col] = f2bf(acc[mt][nt][r] + bcol);
                }
            }
        }
    } else {                                     // Q, skip -> f32
        float* Out = (mat == 0) ? Qo : Yo;
        #pragma unroll
        for (int nt = 0; nt < 2; ++nt) {
            const int col = half * 64 + nqw + nt * 16 + lr;
            const float bcol = bias[col];
            #pragma unroll
            for (int mt = 0; mt < 4; ++mt) {
                const int rbase = row0 + mq + mt * 16 + lq * 4;
                #pragma unroll
                for (int r = 0; r < 4; ++r) {
                    const int row = rbase + r;
                    if (row < N)
                        Out[(size_t)row * DM + col] = acc[mt][nt][r] + bcol;
                }
            }
        }
    }
}

// ---------------- CSR build: histogram -> scan -> scatter --------------------
__global__ __launch_bounds__(256)
void hist_k(const int* __restrict__ dst, int* __restrict__ counts, int E)
{
    int e = blockIdx.x * blockDim.x + threadIdx.x;
    if (e < E) atomicAdd(&counts[dst[e]], 1);
}

__global__ __launch_bounds__(1024)
void scan_k(const int* __restrict__ counts, int* __restrict__ rowptr, int N)
{
    __shared__ int sdata[1024];
    const int t = threadIdx.x;
    const int chunk = (N + 1023) / 1024;
    const int begin = t * chunk;
    const int end   = min(begin + chunk, N);
    int sum = 0;
    for (int i = begin; i < end; ++i) sum += counts[i];
    sdata[t] = sum;
    __syncthreads();
    for (int off = 1; off < 1024; off <<= 1) {
        int v = (t >= off) ? sdata[t - off] : 0;
        __syncthreads();
        if (t >= off) sdata[t] += v;
        __syncthreads();
    }
    int run = (t == 0) ? 0 : sdata[t - 1];
    for (int i = begin; i < end; ++i) {
        rowptr[i] = run;
        run += counts[i];
    }
    if (t == 0) rowptr[N] = sdata[1023];
}

__global__ __launch_bounds__(256)
void scatter_k(const int* __restrict__ src, const int* __restrict__ dst,
               int* __restrict__ cursor, int* __restrict__ esrc, int E)
{
    int e = blockIdx.x * blockDim.x + threadIdx.x;
    if (e >= E) return;
    int pos = atomicAdd(&cursor[dst[e]], 1);
    esrc[pos] = src[e];
}

// ---------------- degree sort (descending counting sort, 256 bins) -----------
// LDS histogram first; one global atomic per (block, nonempty bin)
__global__ __launch_bounds__(256)
void dhist_k(const int* __restrict__ counts, int* __restrict__ dbins, int N)
{
    __shared__ int lb[256];
    const int t = threadIdx.x;
    lb[t] = 0;
    __syncthreads();
    int n = blockIdx.x * 256 + t;
    if (n < N) atomicAdd(&lb[min(counts[n], 255)], 1);
    __syncthreads();
    if (lb[t] > 0) atomicAdd(&dbins[t], lb[t]);
}

__global__ __launch_bounds__(256)
void dscan_k(const int* __restrict__ dbins, int* __restrict__ dcur)
{
    __shared__ int s[256];
    const int t = threadIdx.x;
    s[t] = dbins[255 - t];          // descending degree order
    __syncthreads();
    for (int off = 1; off < 256; off <<= 1) {
        int v = (t >= off) ? s[t - off] : 0;
        __syncthreads();
        if (t >= off) s[t] += v;
        __syncthreads();
    }
    dcur[255 - t] = (t == 0) ? 0 : s[t - 1];   // exclusive start of each bin
}

// LDS-binned: per-block LDS histogram, ONE global atomic per (block, bin)
__global__ __launch_bounds__(256)
void dscatter_k(const int* __restrict__ counts, int* __restrict__ dcur,
                int* __restrict__ perm, int N)
{
    __shared__ int lc[256];     // per-bin count within this block
    __shared__ int lbase[256];  // global base reserved for this block's bin
    const int t = threadIdx.x;
    lc[t] = 0;
    __syncthreads();
    const int n = blockIdx.x * 256 + t;
    int bin = 0, rank = 0;
    const bool valid = (n < N);
    if (valid) {
        bin = min(counts[n], 255);
        rank = atomicAdd(&lc[bin], 1);          // LDS atomic: cheap
    }
    __syncthreads();
    if (lc[t] > 0) lbase[t] = atomicAdd(&dcur[t], lc[t]);
    __syncthreads();
    if (valid) perm[lbase[bin] + rank] = n;
}

// ---------------- fused per-node attention (32 lanes/node, bf16 K/V) ---------
// Yout!=null: write fp32 (+skip Yin). Bout!=null: write bf16 (layer-2 input).
__global__ __launch_bounds__(256)
void node_attn(const float* __restrict__ Q, const ushort* __restrict__ Kb,
               const ushort* __restrict__ Vb,
               const int* __restrict__ rowptr, const int* __restrict__ esrc,
               const int* __restrict__ perm,
               const float* __restrict__ Yin, float* __restrict__ Yout,
               ushort* __restrict__ Bout, int N, int relu)
{
    const int idx = blockIdx.x * 8 + (threadIdx.x >> 5);
    if (idx >= N) return;
    const int nid = perm[idx];
    const int c4 = (threadIdx.x & 31) * 4;      // 4 channels/lane; head=c4>>4
    const float4 q = *(const float4*)(Q + (size_t)nid * DM + c4);
    const int beg = rowptr[nid], end = rowptr[nid + 1];

    float m = -INFINITY, l = 0.f;
    float a0 = 0.f, a1 = 0.f, a2 = 0.f, a3 = 0.f;
    for (int i = beg; i < end; ++i) {
        const int s = esrc[i];
        const uint2 kr = *(const uint2*)(Kb + (size_t)s * DM + c4);
        const uint2 vr = *(const uint2*)(Vb + (size_t)s * DM + c4);
        float p = q.x * bflo(kr.x);
        p = fmaf(q.y, bfhi(kr.x), p);
        p = fmaf(q.z, bflo(kr.y), p);
        p = fmaf(q.w, bfhi(kr.y), p);
        p += __shfl_xor(p, 1, 4);               // head = 4 lanes
        p += __shfl_xor(p, 2, 4);
        p *= SCALE;
        const float v0 = bflo(vr.x), v1 = bfhi(vr.x);
        const float v2 = bflo(vr.y), v3 = bfhi(vr.y);
        if (p <= m) {                            // common case: 1 exp
            const float wgt = __expf(p - m);
            l += wgt;
            a0 = fmaf(wgt, v0, a0); a1 = fmaf(wgt, v1, a1);
            a2 = fmaf(wgt, v2, a2); a3 = fmaf(wgt, v3, a3);
        } else {                                 // new max: rescale
            const float r = __expf(m - p);       // 0 on first edge
            l = fmaf(l, r, 1.f);
            a0 = fmaf(a0, r, v0); a1 = fmaf(a1, r, v1);
            a2 = fmaf(a2, r, v2); a3 = fmaf(a3, r, v3);
            m = p;
        }
    }
    const float inv = (l > 0.f) ? 1.f / l : 0.f;
    float4 y = *(const float4*)(Yin + (size_t)nid * DM + c4);
    y.x = fmaf(a0, inv, y.x); y.y = fmaf(a1, inv, y.y);
    y.z = fmaf(a2, inv, y.z); y.w = fmaf(a3, inv, y.w);
    if (relu) {
        y.x = fmaxf(y.x, 0.f); y.y = fmaxf(y.y, 0.f);
        y.z = fmaxf(y.z, 0.f); y.w = fmaxf(y.w, 0.f);
    }
    if (Yout) *(float4*)(Yout + (size_t)nid * DM + c4) = y;
    if (Bout) {
        uint2 o;
        o.x = pack2bf(y.x, y.y);
        o.y = pack2bf(y.z, y.w);
        *(uint2*)(Bout + (size_t)nid * DM + c4) = o;
    }
}

// ---------------------------------------------------------------------------
extern "C" void kernel_launch(void* const* d_in, const int* in_sizes, int n_in,
                              void* d_out, int out_size, void* d_ws, size_t ws_size,
                              hipStream_t stream)
{
    const float* x   = (const float*)d_in[0];
    const int* eidx  = (const int*)d_in[1];
    const float* qw0 = (const float*)d_in[3];  const float* qb0 = (const float*)d_in[4];
    const float* kw0 = (const float*)d_in[5];  const float* kb0 = (const float*)d_in[6];
    const float* vw0 = (const float*)d_in[7];  const float* vb0 = (const float*)d_in[8];
    const float* sw0 = (const float*)d_in[9];  const float* sb0 = (const float*)d_in[10];
    const float* qw1 = (const float*)d_in[11]; const float* qb1 = (const float*)d_in[12];
    const float* kw1 = (const float*)d_in[13]; const float* kb1 = (const float*)d_in[14];
    const float* vw1 = (const float*)d_in[15]; const float* vb1 = (const float*)d_in[16];
    const float* sw1 = (const float*)d_in[17]; const float* sb1 = (const float*)d_in[18];

    const int N = in_sizes[0] / DM;
    const int E = in_sizes[1] / 2;
    const int* src = eidx;
    const int* dst = eidx + E;

    // ws: Q,S1 [N*128 f32] | Kb,Vb,Xb [N*128 bf16] | WT [4*16384 bf16]
    //     | counts[N] rowptr[N+1] cursor[N] esrc[E] perm[N] dbins[256] dcur[256]
    float* ws  = (float*)d_ws;
    size_t nd  = (size_t)N * DM;
    float* Q   = ws;
    float* S1  = Q + nd;
    ushort* Kb = (ushort*)(S1 + nd);
    ushort* Vb = Kb + nd;
    ushort* Xb = Vb + nd;
    ushort* WT = Xb + nd;
    int* counts = (int*)(WT + 4 * 16384);
    int* rowptr = counts + N;
    int* cursor = rowptr + (N + 1);
    int* esrc   = cursor + N;
    int* perm   = esrc + E;
    int* dbins  = perm + N;
    int* dcur   = dbins + 256;
    float* out  = (float*)d_out;

    // ---- CSR + degree-sorted permutation (shared by both layers) ----
    hipMemsetAsync(counts, 0, (size_t)N * sizeof(int), stream);
    hipMemsetAsync(dbins, 0, 256 * sizeof(int), stream);
    hist_k<<<(E + 255) / 256, 256, 0, stream>>>(dst, counts, E);
    scan_k<<<1, 1024, 0, stream>>>(counts, rowptr, N);
    hipMemcpyAsync(cursor, rowptr, (size_t)N * sizeof(int),
                   hipMemcpyDeviceToDevice, stream);
    scatter_k<<<(E + 255) / 256, 256, 0, stream>>>(src, dst, cursor, esrc, E);
    dhist_k<<<(N + 255) / 256, 256, 0, stream>>>(counts, dbins, N);
    dscan_k<<<1, 256, 0, stream>>>(dbins, dcur);
    dscatter_k<<<(N + 255) / 256, 256, 0, stream>>>(counts, dcur, perm, N);

    const int n4 = N * (DM / 4);
    dim3 ggrid((N + 127) / 128, 8);
    const int ablk = (N + 7) / 8;

    // ---- layer 1: x -> Xb (bf16, relu'd, skip-added) ----
    cvt_x<<<(n4 + 255) / 256, 256, 0, stream>>>(x, Xb, n4);
    cvt_wT<<<dim3(64, 4), 256, 0, stream>>>(qw0, kw0, vw0, sw0, WT);
    gemm_mfma<<<ggrid, 256, 0, stream>>>(Xb, WT, qb0, kb0, vb0, sb0,
                                         Q, Kb, Vb, S1, N);
    node_attn<<<ablk, 256, 0, stream>>>(Q, Kb, Vb, rowptr, esrc, perm,
                                        S1, nullptr, Xb, N, 1);

    // ---- layer 2: Xb -> out (fp32) ----
    cvt_wT<<<dim3(64, 4), 256, 0, stream>>>(qw1, kw1, vw1, sw1, WT);
    gemm_mfma<<<ggrid, 256, 0, stream>>>(Xb, WT, qb1, kb1, vb1, sb1,
                                         Q, Kb, Vb, out, N);
    node_attn<<<ablk, 256, 0, stream>>>(Q, Kb, Vb, rowptr, esrc, perm,
                                        out, out, nullptr, N, 0);
}

// Round 7
// 460.795 us; speedup vs baseline: 1.6825x; 1.1515x over previous
//
#include <hip/hip_runtime.h>
#include <math.h>

// ---------------------------------------------------------------------------
// DDI_GraphTransformer: 2x TransformerConv(H=8, C=16, D=128), N=50000, E=800000
// R6 post-mortem: dhist fix landed (-127us). scan_k now top: 78us single-block
//   scan at 0.15% occupancy.
// R7: three-phase device-wide scan (49 blocks -> tiny block -> grid add);
//   phase 3 also writes cursor (kills the D2D memcpy).
// ---------------------------------------------------------------------------

#define HEADS 8
#define CH 16
#define DM 128
#define SCALE 0.25f

typedef __attribute__((ext_vector_type(8))) short short8;
typedef __attribute__((ext_vector_type(4))) float floatx4;

static __device__ __forceinline__ ushort f2bf(float f) {  // RNE fp32->bf16
    unsigned u = __float_as_uint(f);
    unsigned r = u + 0x7FFFu + ((u >> 16) & 1u);
    return (ushort)(r >> 16);
}
static __device__ __forceinline__ float bflo(unsigned u) {
    return __uint_as_float(u << 16);
}
static __device__ __forceinline__ float bfhi(unsigned u) {
    return __uint_as_float(u & 0xFFFF0000u);
}
static __device__ __forceinline__ unsigned pack2bf(float lo, float hi) {
    return (unsigned)f2bf(lo) | ((unsigned)f2bf(hi) << 16);
}

// ---------------- converters ------------------------------------------------
__global__ __launch_bounds__(256)
void cvt_x(const float* __restrict__ in, ushort* __restrict__ out, int n4)
{
    int i = blockIdx.x * 256 + threadIdx.x;
    if (i >= n4) return;
    float4 v = ((const float4*)in)[i];
    ushort4 s;
    s.x = f2bf(v.x); s.y = f2bf(v.y); s.z = f2bf(v.z); s.w = f2bf(v.w);
    ((ushort4*)out)[i] = s;
}

// WT[mat][n*128+k] = bf16(W[k*128+n]) for 4 weight matrices
__global__ __launch_bounds__(256)
void cvt_wT(const float* __restrict__ W0, const float* __restrict__ W1,
            const float* __restrict__ W2, const float* __restrict__ W3,
            ushort* __restrict__ WT)
{
    const float* W = (blockIdx.y == 0) ? W0 : (blockIdx.y == 1) ? W1
                   : (blockIdx.y == 2) ? W2 : W3;
    int idx = blockIdx.x * 256 + threadIdx.x;   // 0..16383
    int n = idx >> 7, k = idx & 127;
    WT[(size_t)blockIdx.y * 16384 + idx] = f2bf(W[k * 128 + n]);
}

// ---------------- bf16 MFMA GEMM: {Q,Y}=f32, {K,V}=bf16 outputs -------------
#define AP 136   // LDS row pitch in shorts

__global__ __launch_bounds__(256)
void gemm_mfma(const ushort* __restrict__ Xb, const ushort* __restrict__ WT,
               const float* __restrict__ bq, const float* __restrict__ bk,
               const float* __restrict__ bv, const float* __restrict__ bsk,
               float* __restrict__ Qo, ushort* __restrict__ Kb,
               ushort* __restrict__ Vb, float* __restrict__ Yo, int N)
{
    __shared__ ushort As[128 * AP];
    __shared__ ushort Bs[64 * AP];

    const int by   = blockIdx.y;
    const int mat  = by >> 1;
    const int half = by & 1;
    const float* bias = (mat == 0) ? bq : (mat == 1) ? bk : (mat == 2) ? bv : bsk;
    const int row0 = blockIdx.x * 128;
    const int tid  = threadIdx.x;

    #pragma unroll
    for (int i = 0; i < 8; ++i) {
        int id = tid + i * 256;
        int r = id >> 4, ch = id & 15;
        uint4 v = make_uint4(0, 0, 0, 0);
        if (row0 + r < N)
            v = *(const uint4*)(Xb + (size_t)(row0 + r) * DM + ch * 8);
        *(uint4*)(As + r * AP + ch * 8) = v;
    }
    const ushort* Wt = WT + (size_t)mat * 16384 + (size_t)(half * 64) * DM;
    #pragma unroll
    for (int i = 0; i < 4; ++i) {
        int id = tid + i * 256;
        int r = id >> 4, ch = id & 15;
        uint4 v = *(const uint4*)(Wt + (size_t)r * DM + ch * 8);
        *(uint4*)(Bs + r * AP + ch * 8) = v;
    }
    __syncthreads();

    const int lane = tid & 63, w = tid >> 6;
    const int mq = (w >> 1) * 64;
    const int nqw = (w & 1) * 32;
    const int lr = lane & 15, lq = lane >> 4;

    floatx4 acc[4][2] = {};
    #pragma unroll
    for (int ks = 0; ks < 4; ++ks) {
        const int koff = ks * 32 + lq * 8;
        short8 a[4], b[2];
        #pragma unroll
        for (int t = 0; t < 4; ++t)
            a[t] = *(const short8*)(As + (mq + t * 16 + lr) * AP + koff);
        #pragma unroll
        for (int t = 0; t < 2; ++t)
            b[t] = *(const short8*)(Bs + (nqw + t * 16 + lr) * AP + koff);
        #pragma unroll
        for (int mt = 0; mt < 4; ++mt)
            #pragma unroll
            for (int nt = 0; nt < 2; ++nt)
                acc[mt][nt] = __builtin_amdgcn_mfma_f32_16x16x32_bf16(
                    a[mt], b[nt], acc[mt][nt], 0, 0, 0);
    }

    // epilogue: C/D layout col=lane&15, row=(lane>>4)*4+reg
    if (mat == 1 || mat == 2) {                 // K,V -> bf16
        ushort* OutB = (mat == 1) ? Kb : Vb;
        #pragma unroll
        for (int nt = 0; nt < 2; ++nt) {
            const int col = half * 64 + nqw + nt * 16 + lr;
            const float bcol = bias[col];
            #pragma unroll
            for (int mt = 0; mt < 4; ++mt) {
                const int rbase = row0 + mq + mt * 16 + lq * 4;
                #pragma unroll
                for (int r = 0; r < 4; ++r) {
                    const int row = rbase + r;
                    if (row < N)
                        OutB[(size_t)row * DM + col] = f2bf(acc[mt][nt][r] + bcol);
                }
            }
        }
    } else {                                     // Q, skip -> f32
        float* Out = (mat == 0) ? Qo : Yo;
        #pragma unroll
        for (int nt = 0; nt < 2; ++nt) {
            const int col = half * 64 + nqw + nt * 16 + lr;
            const float bcol = bias[col];
            #pragma unroll
            for (int mt = 0; mt < 4; ++mt) {
                const int rbase = row0 + mq + mt * 16 + lq * 4;
                #pragma unroll
                for (int r = 0; r < 4; ++r) {
                    const int row = rbase + r;
                    if (row < N)
                        Out[(size_t)row * DM + col] = acc[mt][nt][r] + bcol;
                }
            }
        }
    }
}

// ---------------- CSR build: histogram -> scan -> scatter --------------------
__global__ __launch_bounds__(256)
void hist_k(const int* __restrict__ dst, int* __restrict__ counts, int E)
{
    int e = blockIdx.x * blockDim.x + threadIdx.x;
    if (e < E) atomicAdd(&counts[dst[e]], 1);
}

// ---- three-phase device-wide exclusive scan (1024 items/block) --------------
__global__ __launch_bounds__(256)
void scan_p1(const int* __restrict__ counts, int* __restrict__ rowptr,
             int* __restrict__ bsums, int N)
{
    __shared__ int s[256];
    const int t = threadIdx.x;
    const int base = blockIdx.x * 1024 + t * 4;
    int c[4];
    int sum = 0;
    #pragma unroll
    for (int j = 0; j < 4; ++j) {
        c[j] = (base + j < N) ? counts[base + j] : 0;
        sum += c[j];
    }
    s[t] = sum;
    __syncthreads();
    for (int off = 1; off < 256; off <<= 1) {
        int v = (t >= off) ? s[t - off] : 0;
        __syncthreads();
        if (t >= off) s[t] += v;
        __syncthreads();
    }
    int ex = (t == 0) ? 0 : s[t - 1];
    #pragma unroll
    for (int j = 0; j < 4; ++j) {
        if (base + j < N) rowptr[base + j] = ex;   // local (block-relative)
        ex += c[j];
    }
    if (t == 255) bsums[blockIdx.x] = s[255];
}

// single tiny block: exclusive scan of nb (<=256) block sums; bbase[nb]=total
__global__ __launch_bounds__(256)
void scan_p2(const int* __restrict__ bsums, int* __restrict__ bbase, int nb)
{
    __shared__ int s[256];
    const int t = threadIdx.x;
    s[t] = (t < nb) ? bsums[t] : 0;
    __syncthreads();
    for (int off = 1; off < 256; off <<= 1) {
        int v = (t >= off) ? s[t - off] : 0;
        __syncthreads();
        if (t >= off) s[t] += v;
        __syncthreads();
    }
    if (t <= nb) bbase[t] = (t == 0) ? 0 : s[t - 1];   // bbase[nb] = total
}

// add block base; also write cursor copy and rowptr[N]
__global__ __launch_bounds__(256)
void scan_p3(int* __restrict__ rowptr, int* __restrict__ cursor,
             const int* __restrict__ bbase, int N, int nb)
{
    int i = blockIdx.x * 256 + threadIdx.x;
    if (i < N) {
        int v = rowptr[i] + bbase[i >> 10];
        rowptr[i] = v;
        cursor[i] = v;
    }
    if (i == 0) rowptr[N] = bbase[nb];
}

__global__ __launch_bounds__(256)
void scatter_k(const int* __restrict__ src, const int* __restrict__ dst,
               int* __restrict__ cursor, int* __restrict__ esrc, int E)
{
    int e = blockIdx.x * blockDim.x + threadIdx.x;
    if (e >= E) return;
    int pos = atomicAdd(&cursor[dst[e]], 1);
    esrc[pos] = src[e];
}

// ---------------- degree sort (descending counting sort, 256 bins) -----------
// LDS histogram first; one global atomic per (block, nonempty bin)
__global__ __launch_bounds__(256)
void dhist_k(const int* __restrict__ counts, int* __restrict__ dbins, int N)
{
    __shared__ int lb[256];
    const int t = threadIdx.x;
    lb[t] = 0;
    __syncthreads();
    int n = blockIdx.x * 256 + t;
    if (n < N) atomicAdd(&lb[min(counts[n], 255)], 1);
    __syncthreads();
    if (lb[t] > 0) atomicAdd(&dbins[t], lb[t]);
}

__global__ __launch_bounds__(256)
void dscan_k(const int* __restrict__ dbins, int* __restrict__ dcur)
{
    __shared__ int s[256];
    const int t = threadIdx.x;
    s[t] = dbins[255 - t];          // descending degree order
    __syncthreads();
    for (int off = 1; off < 256; off <<= 1) {
        int v = (t >= off) ? s[t - off] : 0;
        __syncthreads();
        if (t >= off) s[t] += v;
        __syncthreads();
    }
    dcur[255 - t] = (t == 0) ? 0 : s[t - 1];   // exclusive start of each bin
}

// LDS-binned: per-block LDS histogram, ONE global atomic per (block, bin)
__global__ __launch_bounds__(256)
void dscatter_k(const int* __restrict__ counts, int* __restrict__ dcur,
                int* __restrict__ perm, int N)
{
    __shared__ int lc[256];     // per-bin count within this block
    __shared__ int lbase[256];  // global base reserved for this block's bin
    const int t = threadIdx.x;
    lc[t] = 0;
    __syncthreads();
    const int n = blockIdx.x * 256 + t;
    int bin = 0, rank = 0;
    const bool valid = (n < N);
    if (valid) {
        bin = min(counts[n], 255);
        rank = atomicAdd(&lc[bin], 1);          // LDS atomic: cheap
    }
    __syncthreads();
    if (lc[t] > 0) lbase[t] = atomicAdd(&dcur[t], lc[t]);
    __syncthreads();
    if (valid) perm[lbase[bin] + rank] = n;
}

// ---------------- fused per-node attention (32 lanes/node, bf16 K/V) ---------
// Yout!=null: write fp32 (+skip Yin). Bout!=null: write bf16 (layer-2 input).
__global__ __launch_bounds__(256)
void node_attn(const float* __restrict__ Q, const ushort* __restrict__ Kb,
               const ushort* __restrict__ Vb,
               const int* __restrict__ rowptr, const int* __restrict__ esrc,
               const int* __restrict__ perm,
               const float* __restrict__ Yin, float* __restrict__ Yout,
               ushort* __restrict__ Bout, int N, int relu)
{
    const int idx = blockIdx.x * 8 + (threadIdx.x >> 5);
    if (idx >= N) return;
    const int nid = perm[idx];
    const int c4 = (threadIdx.x & 31) * 4;      // 4 channels/lane; head=c4>>4
    const float4 q = *(const float4*)(Q + (size_t)nid * DM + c4);
    const int beg = rowptr[nid], end = rowptr[nid + 1];

    float m = -INFINITY, l = 0.f;
    float a0 = 0.f, a1 = 0.f, a2 = 0.f, a3 = 0.f;
    for (int i = beg; i < end; ++i) {
        const int s = esrc[i];
        const uint2 kr = *(const uint2*)(Kb + (size_t)s * DM + c4);
        const uint2 vr = *(const uint2*)(Vb + (size_t)s * DM + c4);
        float p = q.x * bflo(kr.x);
        p = fmaf(q.y, bfhi(kr.x), p);
        p = fmaf(q.z, bflo(kr.y), p);
        p = fmaf(q.w, bfhi(kr.y), p);
        p += __shfl_xor(p, 1, 4);               // head = 4 lanes
        p += __shfl_xor(p, 2, 4);
        p *= SCALE;
        const float v0 = bflo(vr.x), v1 = bfhi(vr.x);
        const float v2 = bflo(vr.y), v3 = bfhi(vr.y);
        if (p <= m) {                            // common case: 1 exp
            const float wgt = __expf(p - m);
            l += wgt;
            a0 = fmaf(wgt, v0, a0); a1 = fmaf(wgt, v1, a1);
            a2 = fmaf(wgt, v2, a2); a3 = fmaf(wgt, v3, a3);
        } else {                                 // new max: rescale
            const float r = __expf(m - p);       // 0 on first edge
            l = fmaf(l, r, 1.f);
            a0 = fmaf(a0, r, v0); a1 = fmaf(a1, r, v1);
            a2 = fmaf(a2, r, v2); a3 = fmaf(a3, r, v3);
            m = p;
        }
    }
    const float inv = (l > 0.f) ? 1.f / l : 0.f;
    float4 y = *(const float4*)(Yin + (size_t)nid * DM + c4);
    y.x = fmaf(a0, inv, y.x); y.y = fmaf(a1, inv, y.y);
    y.z = fmaf(a2, inv, y.z); y.w = fmaf(a3, inv, y.w);
    if (relu) {
        y.x = fmaxf(y.x, 0.f); y.y = fmaxf(y.y, 0.f);
        y.z = fmaxf(y.z, 0.f); y.w = fmaxf(y.w, 0.f);
    }
    if (Yout) *(float4*)(Yout + (size_t)nid * DM + c4) = y;
    if (Bout) {
        uint2 o;
        o.x = pack2bf(y.x, y.y);
        o.y = pack2bf(y.z, y.w);
        *(uint2*)(Bout + (size_t)nid * DM + c4) = o;
    }
}

// ---------------------------------------------------------------------------
extern "C" void kernel_launch(void* const* d_in, const int* in_sizes, int n_in,
                              void* d_out, int out_size, void* d_ws, size_t ws_size,
                              hipStream_t stream)
{
    const float* x   = (const float*)d_in[0];
    const int* eidx  = (const int*)d_in[1];
    const float* qw0 = (const float*)d_in[3];  const float* qb0 = (const float*)d_in[4];
    const float* kw0 = (const float*)d_in[5];  const float* kb0 = (const float*)d_in[6];
    const float* vw0 = (const float*)d_in[7];  const float* vb0 = (const float*)d_in[8];
    const float* sw0 = (const float*)d_in[9];  const float* sb0 = (const float*)d_in[10];
    const float* qw1 = (const float*)d_in[11]; const float* qb1 = (const float*)d_in[12];
    const float* kw1 = (const float*)d_in[13]; const float* kb1 = (const float*)d_in[14];
    const float* vw1 = (const float*)d_in[15]; const float* vb1 = (const float*)d_in[16];
    const float* sw1 = (const float*)d_in[17]; const float* sb1 = (const float*)d_in[18];

    const int N = in_sizes[0] / DM;
    const int E = in_sizes[1] / 2;
    const int* src = eidx;
    const int* dst = eidx + E;

    // ws: Q,S1 [N*128 f32] | Kb,Vb,Xb [N*128 bf16] | WT [4*16384 bf16]
    //     | counts[N] rowptr[N+1] cursor[N] esrc[E] perm[N]
    //     | dbins[256] dcur[256] | bsums[256] bbase[257]
    float* ws  = (float*)d_ws;
    size_t nd  = (size_t)N * DM;
    float* Q   = ws;
    float* S1  = Q + nd;
    ushort* Kb = (ushort*)(S1 + nd);
    ushort* Vb = Kb + nd;
    ushort* Xb = Vb + nd;
    ushort* WT = Xb + nd;
    int* counts = (int*)(WT + 4 * 16384);
    int* rowptr = counts + N;
    int* cursor = rowptr + (N + 1);
    int* esrc   = cursor + N;
    int* perm   = esrc + E;
    int* dbins  = perm + N;
    int* dcur   = dbins + 256;
    int* bsums  = dcur + 256;
    int* bbase  = bsums + 256;
    float* out  = (float*)d_out;

    // ---- CSR + degree-sorted permutation (shared by both layers) ----
    const int nb = (N + 1023) / 1024;
    hipMemsetAsync(counts, 0, (size_t)N * sizeof(int), stream);
    hipMemsetAsync(dbins, 0, 256 * sizeof(int), stream);
    hist_k<<<(E + 255) / 256, 256, 0, stream>>>(dst, counts, E);
    scan_p1<<<nb, 256, 0, stream>>>(counts, rowptr, bsums, N);
    scan_p2<<<1, 256, 0, stream>>>(bsums, bbase, nb);
    scan_p3<<<(N + 255) / 256, 256, 0, stream>>>(rowptr, cursor, bbase, N, nb);
    scatter_k<<<(E + 255) / 256, 256, 0, stream>>>(src, dst, cursor, esrc, E);
    dhist_k<<<(N + 255) / 256, 256, 0, stream>>>(counts, dbins, N);
    dscan_k<<<1, 256, 0, stream>>>(dbins, dcur);
    dscatter_k<<<(N + 255) / 256, 256, 0, stream>>>(counts, dcur, perm, N);

    const int n4 = N * (DM / 4);
    dim3 ggrid((N + 127) / 128, 8);
    const int ablk = (N + 7) / 8;

    // ---- layer 1: x -> Xb (bf16, relu'd, skip-added) ----
    cvt_x<<<(n4 + 255) / 256, 256, 0, stream>>>(x, Xb, n4);
    cvt_wT<<<dim3(64, 4), 256, 0, stream>>>(qw0, kw0, vw0, sw0, WT);
    gemm_mfma<<<ggrid, 256, 0, stream>>>(Xb, WT, qb0, kb0, vb0, sb0,
                                         Q, Kb, Vb, S1, N);
    node_attn<<<ablk, 256, 0, stream>>>(Q, Kb, Vb, rowptr, esrc, perm,
                                        S1, nullptr, Xb, N, 1);

    // ---- layer 2: Xb -> out (fp32) ----
    cvt_wT<<<dim3(64, 4), 256, 0, stream>>>(qw1, kw1, vw1, sw1, WT);
    gemm_mfma<<<ggrid, 256, 0, stream>>>(Xb, WT, qb1, kb1, vb1, sb1,
                                         Q, Kb, Vb, out, N);
    node_attn<<<ablk, 256, 0, stream>>>(Q, Kb, Vb, rowptr, esrc, perm,
                                        out, out, nullptr, N, 0);
}

// Round 8
// 458.006 us; speedup vs baseline: 1.6928x; 1.0061x over previous
//
#include <hip/hip_runtime.h>
#include <math.h>

// ---------------------------------------------------------------------------
// DDI_GraphTransformer: 2x TransformerConv(H=8, C=16, D=128), N=50000, E=800000
// R7 post-mortem: scan fix landed. node_attn top (72us, VALUBusy 36%,
//   FETCH 204MB): latency-bound serial gather chain + divergent softmax branch.
// R8: (a) node_attn: 1-deep K/V prefetch + 2-deep esrc prefetch + branchless
//         online softmax (no per-head divergence)
//     (b) gemm: grid.y=4, B-frags straight from global (L2-broadcast), A-tile
//         re-read 8x -> 4x, 64 MFMA/wave
//     (c) cvt_wT8: one dispatch for all 8 weight matrices
// ---------------------------------------------------------------------------

#define HEADS 8
#define CH 16
#define DM 128
#define SCALE 0.25f

typedef __attribute__((ext_vector_type(8))) short short8;
typedef __attribute__((ext_vector_type(4))) float floatx4;

static __device__ __forceinline__ ushort f2bf(float f) {  // RNE fp32->bf16
    unsigned u = __float_as_uint(f);
    unsigned r = u + 0x7FFFu + ((u >> 16) & 1u);
    return (ushort)(r >> 16);
}
static __device__ __forceinline__ float bflo(unsigned u) {
    return __uint_as_float(u << 16);
}
static __device__ __forceinline__ float bfhi(unsigned u) {
    return __uint_as_float(u & 0xFFFF0000u);
}
static __device__ __forceinline__ unsigned pack2bf(float lo, float hi) {
    return (unsigned)f2bf(lo) | ((unsigned)f2bf(hi) << 16);
}

// ---------------- converters ------------------------------------------------
__global__ __launch_bounds__(256)
void cvt_x(const float* __restrict__ in, ushort* __restrict__ out, int n4)
{
    int i = blockIdx.x * 256 + threadIdx.x;
    if (i >= n4) return;
    float4 v = ((const float4*)in)[i];
    ushort4 s;
    s.x = f2bf(v.x); s.y = f2bf(v.y); s.z = f2bf(v.z); s.w = f2bf(v.w);
    ((ushort4*)out)[i] = s;
}

// WT[m][n*128+k] = bf16(W_m[k*128+n]) for all 8 weight matrices (both layers)
__global__ __launch_bounds__(256)
void cvt_wT8(const float* __restrict__ W0, const float* __restrict__ W1,
             const float* __restrict__ W2, const float* __restrict__ W3,
             const float* __restrict__ W4, const float* __restrict__ W5,
             const float* __restrict__ W6, const float* __restrict__ W7,
             ushort* __restrict__ WT)
{
    const float* Ws[8] = {W0, W1, W2, W3, W4, W5, W6, W7};
    const float* W = Ws[blockIdx.y];
    int idx = blockIdx.x * 256 + threadIdx.x;   // 0..16383
    int n = idx >> 7, k = idx & 127;
    WT[(size_t)blockIdx.y * 16384 + idx] = f2bf(W[k * 128 + n]);
}

// ---------------- bf16 MFMA GEMM: {Q,Y}=f32, {K,V}=bf16 outputs -------------
// grid = (ceil(N/128), 4): one matrix per y-block, full 128 cols.
// A tile staged in LDS; B fragments read from global WT (L2-broadcast).
#define AP 136   // LDS row pitch in shorts

__global__ __launch_bounds__(256)
void gemm_mfma(const ushort* __restrict__ Xb, const ushort* __restrict__ WT,
               const float* __restrict__ bq, const float* __restrict__ bk,
               const float* __restrict__ bv, const float* __restrict__ bsk,
               float* __restrict__ Qo, ushort* __restrict__ Kb,
               ushort* __restrict__ Vb, float* __restrict__ Yo, int N)
{
    __shared__ ushort As[128 * AP];

    const int mat = blockIdx.y;
    const float* bias = (mat == 0) ? bq : (mat == 1) ? bk : (mat == 2) ? bv : bsk;
    const int row0 = blockIdx.x * 128;
    const int tid  = threadIdx.x;

    #pragma unroll
    for (int i = 0; i < 8; ++i) {
        int id = tid + i * 256;
        int r = id >> 4, ch = id & 15;
        uint4 v = make_uint4(0, 0, 0, 0);
        if (row0 + r < N)
            v = *(const uint4*)(Xb + (size_t)(row0 + r) * DM + ch * 8);
        *(uint4*)(As + r * AP + ch * 8) = v;
    }
    __syncthreads();

    const int lane = tid & 63, w = tid >> 6;
    const int mq = (w >> 1) * 64;     // wave's 64-row band
    const int nq = (w & 1) * 64;      // wave's 64-col band
    const int lr = lane & 15, lq = lane >> 4;
    const ushort* Wm = WT + (size_t)mat * 16384;

    floatx4 acc[4][4] = {};
    #pragma unroll
    for (int ks = 0; ks < 4; ++ks) {
        const int koff = ks * 32 + lq * 8;
        short8 a[4], b[4];
        #pragma unroll
        for (int t = 0; t < 4; ++t)
            a[t] = *(const short8*)(As + (mq + t * 16 + lr) * AP + koff);
        #pragma unroll
        for (int t = 0; t < 4; ++t)
            b[t] = *(const short8*)(Wm + (size_t)(nq + t * 16 + lr) * DM + koff);
        #pragma unroll
        for (int mt = 0; mt < 4; ++mt)
            #pragma unroll
            for (int nt = 0; nt < 4; ++nt)
                acc[mt][nt] = __builtin_amdgcn_mfma_f32_16x16x32_bf16(
                    a[mt], b[nt], acc[mt][nt], 0, 0, 0);
    }

    // epilogue: C/D layout col=lane&15, row=(lane>>4)*4+reg
    if (mat == 1 || mat == 2) {                 // K,V -> bf16
        ushort* OutB = (mat == 1) ? Kb : Vb;
        #pragma unroll
        for (int nt = 0; nt < 4; ++nt) {
            const int col = nq + nt * 16 + lr;
            const float bcol = bias[col];
            #pragma unroll
            for (int mt = 0; mt < 4; ++mt) {
                const int rbase = row0 + mq + mt * 16 + lq * 4;
                #pragma unroll
                for (int r = 0; r < 4; ++r) {
                    const int row = rbase + r;
                    if (row < N)
                        OutB[(size_t)row * DM + col] = f2bf(acc[mt][nt][r] + bcol);
                }
            }
        }
    } else {                                     // Q, skip -> f32
        float* Out = (mat == 0) ? Qo : Yo;
        #pragma unroll
        for (int nt = 0; nt < 4; ++nt) {
            const int col = nq + nt * 16 + lr;
            const float bcol = bias[col];
            #pragma unroll
            for (int mt = 0; mt < 4; ++mt) {
                const int rbase = row0 + mq + mt * 16 + lq * 4;
                #pragma unroll
                for (int r = 0; r < 4; ++r) {
                    const int row = rbase + r;
                    if (row < N)
                        Out[(size_t)row * DM + col] = acc[mt][nt][r] + bcol;
                }
            }
        }
    }
}

// ---------------- CSR build: histogram -> scan -> scatter --------------------
__global__ __launch_bounds__(256)
void hist_k(const int* __restrict__ dst, int* __restrict__ counts, int E)
{
    int e = blockIdx.x * blockDim.x + threadIdx.x;
    if (e < E) atomicAdd(&counts[dst[e]], 1);
}

// ---- three-phase device-wide exclusive scan (1024 items/block) --------------
__global__ __launch_bounds__(256)
void scan_p1(const int* __restrict__ counts, int* __restrict__ rowptr,
             int* __restrict__ bsums, int N)
{
    __shared__ int s[256];
    const int t = threadIdx.x;
    const int base = blockIdx.x * 1024 + t * 4;
    int c[4];
    int sum = 0;
    #pragma unroll
    for (int j = 0; j < 4; ++j) {
        c[j] = (base + j < N) ? counts[base + j] : 0;
        sum += c[j];
    }
    s[t] = sum;
    __syncthreads();
    for (int off = 1; off < 256; off <<= 1) {
        int v = (t >= off) ? s[t - off] : 0;
        __syncthreads();
        if (t >= off) s[t] += v;
        __syncthreads();
    }
    int ex = (t == 0) ? 0 : s[t - 1];
    #pragma unroll
    for (int j = 0; j < 4; ++j) {
        if (base + j < N) rowptr[base + j] = ex;   // local (block-relative)
        ex += c[j];
    }
    if (t == 255) bsums[blockIdx.x] = s[255];
}

// single tiny block: exclusive scan of nb (<=256) block sums; bbase[nb]=total
__global__ __launch_bounds__(256)
void scan_p2(const int* __restrict__ bsums, int* __restrict__ bbase, int nb)
{
    __shared__ int s[256];
    const int t = threadIdx.x;
    s[t] = (t < nb) ? bsums[t] : 0;
    __syncthreads();
    for (int off = 1; off < 256; off <<= 1) {
        int v = (t >= off) ? s[t - off] : 0;
        __syncthreads();
        if (t >= off) s[t] += v;
        __syncthreads();
    }
    if (t <= nb) bbase[t] = (t == 0) ? 0 : s[t - 1];   // bbase[nb] = total
}

// add block base; also write cursor copy and rowptr[N]
__global__ __launch_bounds__(256)
void scan_p3(int* __restrict__ rowptr, int* __restrict__ cursor,
             const int* __restrict__ bbase, int N, int nb)
{
    int i = blockIdx.x * 256 + threadIdx.x;
    if (i < N) {
        int v = rowptr[i] + bbase[i >> 10];
        rowptr[i] = v;
        cursor[i] = v;
    }
    if (i == 0) rowptr[N] = bbase[nb];
}

__global__ __launch_bounds__(256)
void scatter_k(const int* __restrict__ src, const int* __restrict__ dst,
               int* __restrict__ cursor, int* __restrict__ esrc, int E)
{
    int e = blockIdx.x * blockDim.x + threadIdx.x;
    if (e >= E) return;
    int pos = atomicAdd(&cursor[dst[e]], 1);
    esrc[pos] = src[e];
}

// ---------------- degree sort (descending counting sort, 256 bins) -----------
__global__ __launch_bounds__(256)
void dhist_k(const int* __restrict__ counts, int* __restrict__ dbins, int N)
{
    __shared__ int lb[256];
    const int t = threadIdx.x;
    lb[t] = 0;
    __syncthreads();
    int n = blockIdx.x * 256 + t;
    if (n < N) atomicAdd(&lb[min(counts[n], 255)], 1);
    __syncthreads();
    if (lb[t] > 0) atomicAdd(&dbins[t], lb[t]);
}

__global__ __launch_bounds__(256)
void dscan_k(const int* __restrict__ dbins, int* __restrict__ dcur)
{
    __shared__ int s[256];
    const int t = threadIdx.x;
    s[t] = dbins[255 - t];          // descending degree order
    __syncthreads();
    for (int off = 1; off < 256; off <<= 1) {
        int v = (t >= off) ? s[t - off] : 0;
        __syncthreads();
        if (t >= off) s[t] += v;
        __syncthreads();
    }
    dcur[255 - t] = (t == 0) ? 0 : s[t - 1];   // exclusive start of each bin
}

__global__ __launch_bounds__(256)
void dscatter_k(const int* __restrict__ counts, int* __restrict__ dcur,
                int* __restrict__ perm, int N)
{
    __shared__ int lc[256];
    __shared__ int lbase[256];
    const int t = threadIdx.x;
    lc[t] = 0;
    __syncthreads();
    const int n = blockIdx.x * 256 + t;
    int bin = 0, rank = 0;
    const bool valid = (n < N);
    if (valid) {
        bin = min(counts[n], 255);
        rank = atomicAdd(&lc[bin], 1);
    }
    __syncthreads();
    if (lc[t] > 0) lbase[t] = atomicAdd(&dcur[t], lc[t]);
    __syncthreads();
    if (valid) perm[lbase[bin] + rank] = n;
}

// ---------------- fused per-node attention (pipelined, branchless) -----------
// 32 lanes/node, 4 ch/lane; 1-deep K/V prefetch, 2-deep esrc prefetch.
__global__ __launch_bounds__(256)
void node_attn(const float* __restrict__ Q, const ushort* __restrict__ Kb,
               const ushort* __restrict__ Vb,
               const int* __restrict__ rowptr, const int* __restrict__ esrc,
               const int* __restrict__ perm,
               const float* __restrict__ Yin, float* __restrict__ Yout,
               ushort* __restrict__ Bout, int N, int relu)
{
    const int idx = blockIdx.x * 8 + (threadIdx.x >> 5);
    if (idx >= N) return;
    const int nid = perm[idx];
    const int c4 = (threadIdx.x & 31) * 4;      // 4 channels/lane; head=c4>>4
    const float4 q = *(const float4*)(Q + (size_t)nid * DM + c4);
    const int beg = rowptr[nid], end = rowptr[nid + 1];

    float m = -INFINITY, l = 0.f;
    float a0 = 0.f, a1 = 0.f, a2 = 0.f, a3 = 0.f;

    uint2 kc = make_uint2(0, 0), vc = make_uint2(0, 0);
    int sN = 0;
    if (beg < end) {
        const int s0 = esrc[beg];
        kc = *(const uint2*)(Kb + (size_t)s0 * DM + c4);
        vc = *(const uint2*)(Vb + (size_t)s0 * DM + c4);
        if (beg + 1 < end) sN = esrc[beg + 1];
    }
    for (int i = beg; i < end; ++i) {
        // prefetch edge i+1's K/V and edge i+2's src while computing edge i
        uint2 kn = kc, vn = vc;
        int sNN = sN;
        if (i + 1 < end) {
            kn = *(const uint2*)(Kb + (size_t)sN * DM + c4);
            vn = *(const uint2*)(Vb + (size_t)sN * DM + c4);
            if (i + 2 < end) sNN = esrc[i + 2];
        }
        float p = q.x * bflo(kc.x);
        p = fmaf(q.y, bfhi(kc.x), p);
        p = fmaf(q.z, bflo(kc.y), p);
        p = fmaf(q.w, bfhi(kc.y), p);
        p += __shfl_xor(p, 1, 4);               // head = 4 lanes
        p += __shfl_xor(p, 2, 4);
        p *= SCALE;
        // branchless online softmax (2 exps, no head-group divergence)
        const float nm = fmaxf(m, p);
        const float r  = __expf(m - nm);        // 0 on first edge
        const float wg = __expf(p - nm);
        l  = fmaf(l, r, wg);
        a0 = fmaf(a0, r, wg * bflo(vc.x));
        a1 = fmaf(a1, r, wg * bfhi(vc.x));
        a2 = fmaf(a2, r, wg * bflo(vc.y));
        a3 = fmaf(a3, r, wg * bfhi(vc.y));
        m = nm;
        kc = kn; vc = vn; sN = sNN;
    }
    const float inv = (l > 0.f) ? 1.f / l : 0.f;
    float4 y = *(const float4*)(Yin + (size_t)nid * DM + c4);
    y.x = fmaf(a0, inv, y.x); y.y = fmaf(a1, inv, y.y);
    y.z = fmaf(a2, inv, y.z); y.w = fmaf(a3, inv, y.w);
    if (relu) {
        y.x = fmaxf(y.x, 0.f); y.y = fmaxf(y.y, 0.f);
        y.z = fmaxf(y.z, 0.f); y.w = fmaxf(y.w, 0.f);
    }
    if (Yout) *(float4*)(Yout + (size_t)nid * DM + c4) = y;
    if (Bout) {
        uint2 o;
        o.x = pack2bf(y.x, y.y);
        o.y = pack2bf(y.z, y.w);
        *(uint2*)(Bout + (size_t)nid * DM + c4) = o;
    }
}

// ---------------------------------------------------------------------------
extern "C" void kernel_launch(void* const* d_in, const int* in_sizes, int n_in,
                              void* d_out, int out_size, void* d_ws, size_t ws_size,
                              hipStream_t stream)
{
    const float* x   = (const float*)d_in[0];
    const int* eidx  = (const int*)d_in[1];
    const float* qw0 = (const float*)d_in[3];  const float* qb0 = (const float*)d_in[4];
    const float* kw0 = (const float*)d_in[5];  const float* kb0 = (const float*)d_in[6];
    const float* vw0 = (const float*)d_in[7];  const float* vb0 = (const float*)d_in[8];
    const float* sw0 = (const float*)d_in[9];  const float* sb0 = (const float*)d_in[10];
    const float* qw1 = (const float*)d_in[11]; const float* qb1 = (const float*)d_in[12];
    const float* kw1 = (const float*)d_in[13]; const float* kb1 = (const float*)d_in[14];
    const float* vw1 = (const float*)d_in[15]; const float* vb1 = (const float*)d_in[16];
    const float* sw1 = (const float*)d_in[17]; const float* sb1 = (const float*)d_in[18];

    const int N = in_sizes[0] / DM;
    const int E = in_sizes[1] / 2;
    const int* src = eidx;
    const int* dst = eidx + E;

    // ws: Q,S1 [N*128 f32] | Kb,Vb,Xb [N*128 bf16] | WT [8*16384 bf16]
    //     | counts[N] rowptr[N+1] cursor[N] esrc[E] perm[N]
    //     | dbins[256] dcur[256] bsums[256] bbase[257]
    float* ws  = (float*)d_ws;
    size_t nd  = (size_t)N * DM;
    float* Q   = ws;
    float* S1  = Q + nd;
    ushort* Kb = (ushort*)(S1 + nd);
    ushort* Vb = Kb + nd;
    ushort* Xb = Vb + nd;
    ushort* WT = Xb + nd;
    int* counts = (int*)(WT + 8 * 16384);
    int* rowptr = counts + N;
    int* cursor = rowptr + (N + 1);
    int* esrc   = cursor + N;
    int* perm   = esrc + E;
    int* dbins  = perm + N;
    int* dcur   = dbins + 256;
    int* bsums  = dcur + 256;
    int* bbase  = bsums + 256;
    float* out  = (float*)d_out;

    // ---- CSR + degree-sorted permutation (shared by both layers) ----
    const int nb = (N + 1023) / 1024;
    hipMemsetAsync(counts, 0, (size_t)N * sizeof(int), stream);
    hipMemsetAsync(dbins, 0, 256 * sizeof(int), stream);
    hist_k<<<(E + 255) / 256, 256, 0, stream>>>(dst, counts, E);
    scan_p1<<<nb, 256, 0, stream>>>(counts, rowptr, bsums, N);
    scan_p2<<<1, 256, 0, stream>>>(bsums, bbase, nb);
    scan_p3<<<(N + 255) / 256, 256, 0, stream>>>(rowptr, cursor, bbase, N, nb);
    scatter_k<<<(E + 255) / 256, 256, 0, stream>>>(src, dst, cursor, esrc, E);
    dhist_k<<<(N + 255) / 256, 256, 0, stream>>>(counts, dbins, N);
    dscan_k<<<1, 256, 0, stream>>>(dbins, dcur);
    dscatter_k<<<(N + 255) / 256, 256, 0, stream>>>(counts, dcur, perm, N);

    const int n4 = N * (DM / 4);
    dim3 ggrid((N + 127) / 128, 4);
    const int ablk = (N + 7) / 8;

    // ---- conversions (weights once for both layers) ----
    cvt_x<<<(n4 + 255) / 256, 256, 0, stream>>>(x, Xb, n4);
    cvt_wT8<<<dim3(64, 8), 256, 0, stream>>>(qw0, kw0, vw0, sw0,
                                             qw1, kw1, vw1, sw1, WT);

    // ---- layer 1: x -> Xb (bf16, relu'd, skip-added) ----
    gemm_mfma<<<ggrid, 256, 0, stream>>>(Xb, WT, qb0, kb0, vb0, sb0,
                                         Q, Kb, Vb, S1, N);
    node_attn<<<ablk, 256, 0, stream>>>(Q, Kb, Vb, rowptr, esrc, perm,
                                        S1, nullptr, Xb, N, 1);

    // ---- layer 2: Xb -> out (fp32) ----
    gemm_mfma<<<ggrid, 256, 0, stream>>>(Xb, WT + 4 * 16384, qb1, kb1, vb1, sb1,
                                         Q, Kb, Vb, out, N);
    node_attn<<<ablk, 256, 0, stream>>>(Q, Kb, Vb, rowptr, esrc, perm,
                                        out, out, nullptr, N, 0);
}

// Round 10
// 441.084 us; speedup vs baseline: 1.7577x; 1.0384x over previous
//
#include <hip/hip_runtime.h>
#include <math.h>

// ---------------------------------------------------------------------------
// DDI_GraphTransformer: 2x TransformerConv(H=8, C=16, D=128), N=50000, E=800000
// R9 post-mortem: NaN from staging bug — treated uint4 as 16 shorts (it's 8);
//   half of each LDS row left unwritten (poison -> NaN via MFMA).
// R10: fix staging (1024 x 8-short chunks, 4 iters); rest identical to R9:
//   one block per 64-row band computes ALL FOUR matrices, A-frags hoisted to
//   registers, B from L2-resident WT, Xb fetched once.
// ---------------------------------------------------------------------------

#define HEADS 8
#define CH 16
#define DM 128
#define SCALE 0.25f

typedef __attribute__((ext_vector_type(8))) short short8;
typedef __attribute__((ext_vector_type(4))) float floatx4;

static __device__ __forceinline__ ushort f2bf(float f) {  // RNE fp32->bf16
    unsigned u = __float_as_uint(f);
    unsigned r = u + 0x7FFFu + ((u >> 16) & 1u);
    return (ushort)(r >> 16);
}
static __device__ __forceinline__ float bflo(unsigned u) {
    return __uint_as_float(u << 16);
}
static __device__ __forceinline__ float bfhi(unsigned u) {
    return __uint_as_float(u & 0xFFFF0000u);
}
static __device__ __forceinline__ unsigned pack2bf(float lo, float hi) {
    return (unsigned)f2bf(lo) | ((unsigned)f2bf(hi) << 16);
}

// ---------------- converters ------------------------------------------------
__global__ __launch_bounds__(256)
void cvt_x(const float* __restrict__ in, ushort* __restrict__ out, int n4)
{
    int i = blockIdx.x * 256 + threadIdx.x;
    if (i >= n4) return;
    float4 v = ((const float4*)in)[i];
    ushort4 s;
    s.x = f2bf(v.x); s.y = f2bf(v.y); s.z = f2bf(v.z); s.w = f2bf(v.w);
    ((ushort4*)out)[i] = s;
}

// WT[m][n*128+k] = bf16(W_m[k*128+n]) for all 8 weight matrices (both layers)
__global__ __launch_bounds__(256)
void cvt_wT8(const float* __restrict__ W0, const float* __restrict__ W1,
             const float* __restrict__ W2, const float* __restrict__ W3,
             const float* __restrict__ W4, const float* __restrict__ W5,
             const float* __restrict__ W6, const float* __restrict__ W7,
             ushort* __restrict__ WT)
{
    const float* Ws[8] = {W0, W1, W2, W3, W4, W5, W6, W7};
    const float* W = Ws[blockIdx.y];
    int idx = blockIdx.x * 256 + threadIdx.x;   // 0..16383
    int n = idx >> 7, k = idx & 127;
    WT[(size_t)blockIdx.y * 16384 + idx] = f2bf(W[k * 128 + n]);
}

// ---------------- bf16 MFMA GEMM: all 4 mats per block ----------------------
// grid = ceil(N/64) blocks x 256 thr (4 waves). Wave w owns cols [w*32,w*32+32)
// for all four matrices. A: LDS once -> registers. B: global WT (L2-resident).
#define AP 136   // LDS row pitch in shorts

__global__ __launch_bounds__(256)
void gemm_mfma(const ushort* __restrict__ Xb, const ushort* __restrict__ WT,
               const float* __restrict__ bq, const float* __restrict__ bk,
               const float* __restrict__ bv, const float* __restrict__ bsk,
               float* __restrict__ Qo, ushort* __restrict__ Kb,
               ushort* __restrict__ Vb, float* __restrict__ Yo, int N)
{
    __shared__ ushort As[64 * AP];

    const int row0 = blockIdx.x * 64;
    const int tid  = threadIdx.x;

    // stage 64 rows x 128 shorts = 1024 x 8-short (16B) chunks / 256 thr
    #pragma unroll
    for (int i = 0; i < 4; ++i) {
        int id = tid + i * 256;          // 0..1023
        int r = id >> 4, ch = id & 15;   // 16 x 8-short chunks per row
        uint4 v = make_uint4(0, 0, 0, 0);
        if (row0 + r < N)
            v = *(const uint4*)(Xb + (size_t)(row0 + r) * DM + ch * 8);
        *(uint4*)(As + r * AP + ch * 8) = v;
    }
    __syncthreads();

    const int lane = tid & 63, w = tid >> 6;
    const int nq = w * 32;               // wave's 32-col band
    const int lr = lane & 15, lq = lane >> 4;

    // hoist ALL A-fragments to registers (read LDS once, reuse for 4 mats)
    short8 a[4][4];                      // [ks][mt]
    #pragma unroll
    for (int ks = 0; ks < 4; ++ks) {
        const int koff = ks * 32 + lq * 8;
        #pragma unroll
        for (int mt = 0; mt < 4; ++mt)
            a[ks][mt] = *(const short8*)(As + (mt * 16 + lr) * AP + koff);
    }

    #pragma unroll
    for (int mat = 0; mat < 4; ++mat) {
        const ushort* Wm = WT + (size_t)mat * 16384;
        const float* bias = (mat == 0) ? bq : (mat == 1) ? bk
                          : (mat == 2) ? bv : bsk;
        floatx4 acc[4][2] = {};
        #pragma unroll
        for (int ks = 0; ks < 4; ++ks) {
            const int koff = ks * 32 + lq * 8;
            short8 b[2];
            #pragma unroll
            for (int t = 0; t < 2; ++t)
                b[t] = *(const short8*)(Wm + (size_t)(nq + t * 16 + lr) * DM + koff);
            #pragma unroll
            for (int mt = 0; mt < 4; ++mt)
                #pragma unroll
                for (int nt = 0; nt < 2; ++nt)
                    acc[mt][nt] = __builtin_amdgcn_mfma_f32_16x16x32_bf16(
                        a[ks][mt], b[nt], acc[mt][nt], 0, 0, 0);
        }
        // epilogue: C/D layout col=lane&15, row=(lane>>4)*4+reg
        if (mat == 1 || mat == 2) {      // K,V -> bf16
            ushort* OutB = (mat == 1) ? Kb : Vb;
            #pragma unroll
            for (int nt = 0; nt < 2; ++nt) {
                const int col = nq + nt * 16 + lr;
                const float bcol = bias[col];
                #pragma unroll
                for (int mt = 0; mt < 4; ++mt) {
                    const int rbase = row0 + mt * 16 + lq * 4;
                    #pragma unroll
                    for (int r = 0; r < 4; ++r) {
                        const int row = rbase + r;
                        if (row < N)
                            OutB[(size_t)row * DM + col] = f2bf(acc[mt][nt][r] + bcol);
                    }
                }
            }
        } else {                          // Q, skip -> f32
            float* Out = (mat == 0) ? Qo : Yo;
            #pragma unroll
            for (int nt = 0; nt < 2; ++nt) {
                const int col = nq + nt * 16 + lr;
                const float bcol = bias[col];
                #pragma unroll
                for (int mt = 0; mt < 4; ++mt) {
                    const int rbase = row0 + mt * 16 + lq * 4;
                    #pragma unroll
                    for (int r = 0; r < 4; ++r) {
                        const int row = rbase + r;
                        if (row < N)
                            Out[(size_t)row * DM + col] = acc[mt][nt][r] + bcol;
                    }
                }
            }
        }
    }
}

// ---------------- CSR build: histogram -> scan -> scatter --------------------
__global__ __launch_bounds__(256)
void hist_k(const int* __restrict__ dst, int* __restrict__ counts, int E)
{
    int e = blockIdx.x * blockDim.x + threadIdx.x;
    if (e < E) atomicAdd(&counts[dst[e]], 1);
}

// ---- three-phase device-wide exclusive scan (1024 items/block) --------------
__global__ __launch_bounds__(256)
void scan_p1(const int* __restrict__ counts, int* __restrict__ rowptr,
             int* __restrict__ bsums, int N)
{
    __shared__ int s[256];
    const int t = threadIdx.x;
    const int base = blockIdx.x * 1024 + t * 4;
    int c[4];
    int sum = 0;
    #pragma unroll
    for (int j = 0; j < 4; ++j) {
        c[j] = (base + j < N) ? counts[base + j] : 0;
        sum += c[j];
    }
    s[t] = sum;
    __syncthreads();
    for (int off = 1; off < 256; off <<= 1) {
        int v = (t >= off) ? s[t - off] : 0;
        __syncthreads();
        if (t >= off) s[t] += v;
        __syncthreads();
    }
    int ex = (t == 0) ? 0 : s[t - 1];
    #pragma unroll
    for (int j = 0; j < 4; ++j) {
        if (base + j < N) rowptr[base + j] = ex;   // local (block-relative)
        ex += c[j];
    }
    if (t == 255) bsums[blockIdx.x] = s[255];
}

__global__ __launch_bounds__(256)
void scan_p2(const int* __restrict__ bsums, int* __restrict__ bbase, int nb)
{
    __shared__ int s[256];
    const int t = threadIdx.x;
    s[t] = (t < nb) ? bsums[t] : 0;
    __syncthreads();
    for (int off = 1; off < 256; off <<= 1) {
        int v = (t >= off) ? s[t - off] : 0;
        __syncthreads();
        if (t >= off) s[t] += v;
        __syncthreads();
    }
    if (t <= nb) bbase[t] = (t == 0) ? 0 : s[t - 1];   // bbase[nb] = total
}

__global__ __launch_bounds__(256)
void scan_p3(int* __restrict__ rowptr, int* __restrict__ cursor,
             const int* __restrict__ bbase, int N, int nb)
{
    int i = blockIdx.x * 256 + threadIdx.x;
    if (i < N) {
        int v = rowptr[i] + bbase[i >> 10];
        rowptr[i] = v;
        cursor[i] = v;
    }
    if (i == 0) rowptr[N] = bbase[nb];
}

__global__ __launch_bounds__(256)
void scatter_k(const int* __restrict__ src, const int* __restrict__ dst,
               int* __restrict__ cursor, int* __restrict__ esrc, int E)
{
    int e = blockIdx.x * blockDim.x + threadIdx.x;
    if (e >= E) return;
    int pos = atomicAdd(&cursor[dst[e]], 1);
    esrc[pos] = src[e];
}

// ---------------- degree sort (descending counting sort, 256 bins) -----------
__global__ __launch_bounds__(256)
void dhist_k(const int* __restrict__ counts, int* __restrict__ dbins, int N)
{
    __shared__ int lb[256];
    const int t = threadIdx.x;
    lb[t] = 0;
    __syncthreads();
    int n = blockIdx.x * 256 + t;
    if (n < N) atomicAdd(&lb[min(counts[n], 255)], 1);
    __syncthreads();
    if (lb[t] > 0) atomicAdd(&dbins[t], lb[t]);
}

__global__ __launch_bounds__(256)
void dscan_k(const int* __restrict__ dbins, int* __restrict__ dcur)
{
    __shared__ int s[256];
    const int t = threadIdx.x;
    s[t] = dbins[255 - t];          // descending degree order
    __syncthreads();
    for (int off = 1; off < 256; off <<= 1) {
        int v = (t >= off) ? s[t - off] : 0;
        __syncthreads();
        if (t >= off) s[t] += v;
        __syncthreads();
    }
    dcur[255 - t] = (t == 0) ? 0 : s[t - 1];   // exclusive start of each bin
}

__global__ __launch_bounds__(256)
void dscatter_k(const int* __restrict__ counts, int* __restrict__ dcur,
                int* __restrict__ perm, int N)
{
    __shared__ int lc[256];
    __shared__ int lbase[256];
    const int t = threadIdx.x;
    lc[t] = 0;
    __syncthreads();
    const int n = blockIdx.x * 256 + t;
    int bin = 0, rank = 0;
    const bool valid = (n < N);
    if (valid) {
        bin = min(counts[n], 255);
        rank = atomicAdd(&lc[bin], 1);
    }
    __syncthreads();
    if (lc[t] > 0) lbase[t] = atomicAdd(&dcur[t], lc[t]);
    __syncthreads();
    if (valid) perm[lbase[bin] + rank] = n;
}

// ---------------- fused per-node attention (pipelined, branchless) -----------
// 32 lanes/node, 4 ch/lane; 1-deep K/V prefetch, 2-deep esrc prefetch.
__global__ __launch_bounds__(256)
void node_attn(const float* __restrict__ Q, const ushort* __restrict__ Kb,
               const ushort* __restrict__ Vb,
               const int* __restrict__ rowptr, const int* __restrict__ esrc,
               const int* __restrict__ perm,
               const float* __restrict__ Yin, float* __restrict__ Yout,
               ushort* __restrict__ Bout, int N, int relu)
{
    const int idx = blockIdx.x * 8 + (threadIdx.x >> 5);
    if (idx >= N) return;
    const int nid = perm[idx];
    const int c4 = (threadIdx.x & 31) * 4;      // 4 channels/lane; head=c4>>4
    const float4 q = *(const float4*)(Q + (size_t)nid * DM + c4);
    const int beg = rowptr[nid], end = rowptr[nid + 1];

    float m = -INFINITY, l = 0.f;
    float a0 = 0.f, a1 = 0.f, a2 = 0.f, a3 = 0.f;

    uint2 kc = make_uint2(0, 0), vc = make_uint2(0, 0);
    int sN = 0;
    if (beg < end) {
        const int s0 = esrc[beg];
        kc = *(const uint2*)(Kb + (size_t)s0 * DM + c4);
        vc = *(const uint2*)(Vb + (size_t)s0 * DM + c4);
        if (beg + 1 < end) sN = esrc[beg + 1];
    }
    for (int i = beg; i < end; ++i) {
        uint2 kn = kc, vn = vc;
        int sNN = sN;
        if (i + 1 < end) {
            kn = *(const uint2*)(Kb + (size_t)sN * DM + c4);
            vn = *(const uint2*)(Vb + (size_t)sN * DM + c4);
            if (i + 2 < end) sNN = esrc[i + 2];
        }
        float p = q.x * bflo(kc.x);
        p = fmaf(q.y, bfhi(kc.x), p);
        p = fmaf(q.z, bflo(kc.y), p);
        p = fmaf(q.w, bfhi(kc.y), p);
        p += __shfl_xor(p, 1, 4);               // head = 4 lanes
        p += __shfl_xor(p, 2, 4);
        p *= SCALE;
        const float nm = fmaxf(m, p);
        const float r  = __expf(m - nm);        // 0 on first edge
        const float wg = __expf(p - nm);
        l  = fmaf(l, r, wg);
        a0 = fmaf(a0, r, wg * bflo(vc.x));
        a1 = fmaf(a1, r, wg * bfhi(vc.x));
        a2 = fmaf(a2, r, wg * bflo(vc.y));
        a3 = fmaf(a3, r, wg * bfhi(vc.y));
        m = nm;
        kc = kn; vc = vn; sN = sNN;
    }
    const float inv = (l > 0.f) ? 1.f / l : 0.f;
    float4 y = *(const float4*)(Yin + (size_t)nid * DM + c4);
    y.x = fmaf(a0, inv, y.x); y.y = fmaf(a1, inv, y.y);
    y.z = fmaf(a2, inv, y.z); y.w = fmaf(a3, inv, y.w);
    if (relu) {
        y.x = fmaxf(y.x, 0.f); y.y = fmaxf(y.y, 0.f);
        y.z = fmaxf(y.z, 0.f); y.w = fmaxf(y.w, 0.f);
    }
    if (Yout) *(float4*)(Yout + (size_t)nid * DM + c4) = y;
    if (Bout) {
        uint2 o;
        o.x = pack2bf(y.x, y.y);
        o.y = pack2bf(y.z, y.w);
        *(uint2*)(Bout + (size_t)nid * DM + c4) = o;
    }
}

// ---------------------------------------------------------------------------
extern "C" void kernel_launch(void* const* d_in, const int* in_sizes, int n_in,
                              void* d_out, int out_size, void* d_ws, size_t ws_size,
                              hipStream_t stream)
{
    const float* x   = (const float*)d_in[0];
    const int* eidx  = (const int*)d_in[1];
    const float* qw0 = (const float*)d_in[3];  const float* qb0 = (const float*)d_in[4];
    const float* kw0 = (const float*)d_in[5];  const float* kb0 = (const float*)d_in[6];
    const float* vw0 = (const float*)d_in[7];  const float* vb0 = (const float*)d_in[8];
    const float* sw0 = (const float*)d_in[9];  const float* sb0 = (const float*)d_in[10];
    const float* qw1 = (const float*)d_in[11]; const float* qb1 = (const float*)d_in[12];
    const float* kw1 = (const float*)d_in[13]; const float* kb1 = (const float*)d_in[14];
    const float* vw1 = (const float*)d_in[15]; const float* vb1 = (const float*)d_in[16];
    const float* sw1 = (const float*)d_in[17]; const float* sb1 = (const float*)d_in[18];

    const int N = in_sizes[0] / DM;
    const int E = in_sizes[1] / 2;
    const int* src = eidx;
    const int* dst = eidx + E;

    // ws: Q,S1 [N*128 f32] | Kb,Vb,Xb [N*128 bf16] | WT [8*16384 bf16]
    //     | counts[N] rowptr[N+1] cursor[N] esrc[E] perm[N]
    //     | dbins[256] dcur[256] bsums[256] bbase[257]
    float* ws  = (float*)d_ws;
    size_t nd  = (size_t)N * DM;
    float* Q   = ws;
    float* S1  = Q + nd;
    ushort* Kb = (ushort*)(S1 + nd);
    ushort* Vb = Kb + nd;
    ushort* Xb = Vb + nd;
    ushort* WT = Xb + nd;
    int* counts = (int*)(WT + 8 * 16384);
    int* rowptr = counts + N;
    int* cursor = rowptr + (N + 1);
    int* esrc   = cursor + N;
    int* perm   = esrc + E;
    int* dbins  = perm + N;
    int* dcur   = dbins + 256;
    int* bsums  = dcur + 256;
    int* bbase  = bsums + 256;
    float* out  = (float*)d_out;

    // ---- CSR + degree-sorted permutation (shared by both layers) ----
    const int nb = (N + 1023) / 1024;
    hipMemsetAsync(counts, 0, (size_t)N * sizeof(int), stream);
    hipMemsetAsync(dbins, 0, 256 * sizeof(int), stream);
    hist_k<<<(E + 255) / 256, 256, 0, stream>>>(dst, counts, E);
    scan_p1<<<nb, 256, 0, stream>>>(counts, rowptr, bsums, N);
    scan_p2<<<1, 256, 0, stream>>>(bsums, bbase, nb);
    scan_p3<<<(N + 255) / 256, 256, 0, stream>>>(rowptr, cursor, bbase, N, nb);
    scatter_k<<<(E + 255) / 256, 256, 0, stream>>>(src, dst, cursor, esrc, E);
    dhist_k<<<(N + 255) / 256, 256, 0, stream>>>(counts, dbins, N);
    dscan_k<<<1, 256, 0, stream>>>(dbins, dcur);
    dscatter_k<<<(N + 255) / 256, 256, 0, stream>>>(counts, dcur, perm, N);

    const int n4 = N * (DM / 4);
    const int ggrid = (N + 63) / 64;
    const int ablk = (N + 7) / 8;

    // ---- conversions (weights once for both layers) ----
    cvt_x<<<(n4 + 255) / 256, 256, 0, stream>>>(x, Xb, n4);
    cvt_wT8<<<dim3(64, 8), 256, 0, stream>>>(qw0, kw0, vw0, sw0,
                                             qw1, kw1, vw1, sw1, WT);

    // ---- layer 1: x -> Xb (bf16, relu'd, skip-added) ----
    gemm_mfma<<<ggrid, 256, 0, stream>>>(Xb, WT, qb0, kb0, vb0, sb0,
                                         Q, Kb, Vb, S1, N);
    node_attn<<<ablk, 256, 0, stream>>>(Q, Kb, Vb, rowptr, esrc, perm,
                                        S1, nullptr, Xb, N, 1);

    // ---- layer 2: Xb -> out (fp32) ----
    gemm_mfma<<<ggrid, 256, 0, stream>>>(Xb, WT + 4 * 16384, qb1, kb1, vb1, sb1,
                                         Q, Kb, Vb, out, N);
    node_attn<<<ablk, 256, 0, stream>>>(Q, Kb, Vb, rowptr, esrc, perm,
                                        out, out, nullptr, N, 0);
}